// Round 7
// baseline (462.776 us; speedup 1.0000x reference)
//
#include <hip/hip_runtime.h>
#include <math.h>

// Mamba block. GEMMs: f16 split-2 ([hi|lo] planes). A-tile via global_load_lds
// 3-ring (16KB/buf, distance-2, counted vmcnt + raw s_barrier); W fragments
// direct global->VGPR with 1-iter register prefetch (no LDS for W).
// Chunked parallel scan, fused conv/silu.

typedef _Float16 half8 __attribute__((ext_vector_type(8)));
typedef float floatx4 __attribute__((ext_vector_type(4)));

#define NSTATE 16
#define NCHUNK 32
#define LCHUNK 32

__device__ __forceinline__ void gload_lds16(const _Float16* g, _Float16* l) {
    __builtin_amdgcn_global_load_lds(
        (const __attribute__((address_space(1))) unsigned int*)g,
        (__attribute__((address_space(3))) unsigned int*)l, 16, 0, 0);
}

// ---------- converter: fp32 [R][K] -> f16 [Rpad][2K] = [hi | lo] ----------
__global__ __launch_bounds__(256) void convert_split(
    const float* __restrict__ src, _Float16* __restrict__ dst,
    int R, int Rpad, int K)
{
    int idx = blockIdx.x * 256 + threadIdx.x;
    int nck = K >> 3;
    int r = idx / nck;
    int g = idx - r * nck;
    if (r >= Rpad) return;
    half8 h, l;
    if (r < R) {
        const float* sp = src + (size_t)r * K + g * 8;
        #pragma unroll
        for (int e = 0; e < 8; ++e) {
            float x = sp[e];
            _Float16 hv = (_Float16)x;
            h[e] = hv;
            l[e] = (_Float16)(x - (float)hv);
        }
    } else {
        #pragma unroll
        for (int e = 0; e < 8; ++e) { h[e] = (_Float16)0.f; l[e] = (_Float16)0.f; }
    }
    _Float16* dp = dst + (size_t)r * 2 * K + g * 8;
    *(half8*)dp = h;
    *(half8*)(dp + K) = l;
}

// ---------- MFMA GEMM: C[M,N](fp32) = A2[M,2K](f16 hi|lo) @ W2[Npad,2K]^T ----
// 128x128 tile, 4 waves (2x2), wave tile 64x64. BK=32 fp32 elements.
// LDS: 3-ring x {Ah[128][32] | Al[128][32]} = 3 x 16KB. W: direct global->reg.
// Per-iter VMEM per wave: 4 A-stages + 8 W-loads.
// Steady-state wait for A(k): younger = W(k-1):8 + A(k+1):4 + W(k):8 = 20.
#define GITER(KK, WC, WN, NW)                                                  \
  {                                                                            \
    asm volatile("s_waitcnt vmcnt(" NW ")" ::: "memory");                      \
    __builtin_amdgcn_s_barrier();                                              \
    __builtin_amdgcn_sched_barrier(0);                                         \
    int kp = (KK) + 2; if (kp > kSteps - 1) kp = kSteps - 1;                   \
    _Float16* tb = lds + (((KK) + 2) % 3) * 8192 + dstBase;                    \
    _Pragma("unroll")                                                          \
    for (int j = 0; j < 4; ++j)                                                \
        gload_lds16(pA + (size_t)(j & 1) * 16 * K2 + (j >> 1) * K + kp * 32,   \
                    tb + (j >> 1) * 4096 + (j & 1) * 512);                     \
    __builtin_amdgcn_sched_barrier(0);                                         \
    int kw = (KK) + 1; if (kw > kSteps - 1) kw = kSteps - 1;                   \
    _Pragma("unroll")                                                          \
    for (int ni = 0; ni < 4; ++ni) {                                           \
        WN[ni]     = *(const half8*)(pW + (size_t)ni * 16 * K2 + kw * 32);     \
        WN[4 + ni] = *(const half8*)(pW + (size_t)ni * 16 * K2 + K + kw * 32); \
    }                                                                          \
    __builtin_amdgcn_sched_barrier(0);                                         \
    const _Float16* buf = lds + ((KK) % 3) * 8192;                             \
    half8 af0[4], af1[4];                                                      \
    _Pragma("unroll")                                                          \
    for (int mi = 0; mi < 4; ++mi) {                                           \
        af0[mi] = *(const half8*)(buf + aoffBase + mi * 512);                  \
        af1[mi] = *(const half8*)(buf + 4096 + aoffBase + mi * 512);           \
    }                                                                          \
    _Pragma("unroll")                                                          \
    for (int mi = 0; mi < 4; ++mi)                                             \
      _Pragma("unroll")                                                        \
      for (int ni = 0; ni < 4; ++ni) {                                         \
        floatx4 a = acc[mi][ni];                                               \
        a = __builtin_amdgcn_mfma_f32_16x16x32_f16(af0[mi], WC[ni], a, 0,0,0); \
        a = __builtin_amdgcn_mfma_f32_16x16x32_f16(af0[mi], WC[4+ni], a,0,0,0);\
        a = __builtin_amdgcn_mfma_f32_16x16x32_f16(af1[mi], WC[ni], a, 0,0,0); \
        acc[mi][ni] = a;                                                       \
      }                                                                        \
  }

__global__ __launch_bounds__(256, 2) void hgemm3(
    const _Float16* __restrict__ A2, const _Float16* __restrict__ W2,
    const float* __restrict__ bias, float* __restrict__ C, float* __restrict__ C2,
    int colSplit, int ldc, int Nvalid, int K, int kSteps,
    int kzStride, size_t zStrideC)
{
    __shared__ _Float16 lds[3 * 8192];   // 48 KB

    // XCD-chunked block swizzle (gridDim.y == 16, nwg % 8 == 0)
    const int nbx = gridDim.x;
    const int h = blockIdx.y * nbx + blockIdx.x;
    const int cpx = (nbx * 16) >> 3;
    const int e = (h & 7) * cpx + (h >> 3);
    const int bx = e >> 4, by = e & 15;

    const int tid = threadIdx.x;
    const int lane = tid & 63;
    const int wid = tid >> 6;
    const int wm = wid >> 1, wn = wid & 1;
    const int m0 = by * 128, n0 = bx * 128;
    const int kg = lane >> 4, fr = lane & 15;
    const size_t K2 = (size_t)2 * K;
    const int kBegin = blockIdx.z * kzStride;

    // A staging: wave wid stages rows wid*32..wid*32+31, both limbs.
    // Source chunk-swizzled so LDS[r][c] = G[r][c ^ ((r>>1)&3)].
    const int scol = ((lane & 3) ^ ((lane >> 3) & 3)) << 3;
    const _Float16* pA = A2 + (size_t)(m0 + wid * 32 + (lane >> 2)) * K2 + kBegin + scol;
    const int dstBase = wid * 32 * 32;   // halfs, within a plane

    // W direct-load pointer (per lane: row n0+wn*64+fr, chunk kg)
    const _Float16* pW = W2 + (size_t)(n0 + wn * 64 + fr) * K2 + kBegin + kg * 8;

    floatx4 acc[4][4];
    #pragma unroll
    for (int mi = 0; mi < 4; ++mi)
        #pragma unroll
        for (int ni = 0; ni < 4; ++ni)
            acc[mi][ni] = (floatx4){0.f, 0.f, 0.f, 0.f};

    const int rsw = (fr >> 1) & 3;
    const int aoffBase = (wm * 64 + fr) * 32 + ((kg ^ rsw) << 3);

    half8 wA[8], wB[8];

    // prologue: stage A(0)->buf0, A(1)->buf1; load W(0)->wA
    #pragma unroll
    for (int j = 0; j < 4; ++j)
        gload_lds16(pA + (size_t)(j & 1) * 16 * K2 + (j >> 1) * K,
                    lds + (j >> 1) * 4096 + dstBase + (j & 1) * 512);
    #pragma unroll
    for (int j = 0; j < 4; ++j)
        gload_lds16(pA + (size_t)(j & 1) * 16 * K2 + (j >> 1) * K + 32,
                    lds + 8192 + (j >> 1) * 4096 + dstBase + (j & 1) * 512);
    #pragma unroll
    for (int ni = 0; ni < 4; ++ni) {
        wA[ni]     = *(const half8*)(pW + (size_t)ni * 16 * K2);
        wA[4 + ni] = *(const half8*)(pW + (size_t)ni * 16 * K2 + K);
    }

    GITER(0, wA, wB, "12")
    for (int k = 1; k + 1 < kSteps; k += 2) {
        GITER(k, wB, wA, "20")
        GITER(k + 1, wA, wB, "20")
    }
    GITER(kSteps - 1, wB, wA, "20")

    asm volatile("s_waitcnt vmcnt(0)" ::: "memory");  // drain DMA before exit

    // epilogue: col = fr, row-in-frag = kg*4 + r
    float* Cz = C + blockIdx.z * zStrideC;
    #pragma unroll
    for (int ni = 0; ni < 4; ++ni) {
        int nn = n0 + wn * 64 + ni * 16 + fr;
        if (nn >= Nvalid) continue;
        float bv = bias ? bias[nn] : 0.f;
        float* Cp = Cz;
        int col = nn;
        if (C2 && nn >= colSplit) { Cp = C2; col = nn - colSplit; }
        #pragma unroll
        for (int mi = 0; mi < 4; ++mi) {
            int mm = m0 + wm * 64 + mi * 16 + kg * 4;
            float* p = Cp + (size_t)mm * ldc + col;
            #pragma unroll
            for (int r = 0; r < 4; ++r)
                p[(size_t)r * ldc] = acc[mi][ni][r] + bv;
        }
    }
}

// ---------- conv + silu, emits f16 [hi|lo] layout (width 2*2048) ----------
__global__ __launch_bounds__(256) void conv_silu2(
    const float* __restrict__ xc, const float* __restrict__ conv_w,
    const float* __restrict__ conv_b, _Float16* __restrict__ xcs2)
{
    const int D = 2048, L = 1024;
    int idx = blockIdx.x * 256 + threadIdx.x;
    int g = idx & 255;
    int l = (idx >> 8) & (L - 1);
    int b = idx >> 18;
    int d0 = g * 8;
    int row = b * L + l;

    float a[8];
    #pragma unroll
    for (int j = 0; j < 8; ++j) a[j] = conv_b[d0 + j];
    #pragma unroll
    for (int t = 0; t < 4; ++t) {
        int lt = l - 3 + t;
        if (lt >= 0) {
            const float* rp = xc + (size_t)(b * L + lt) * D + d0;
            #pragma unroll
            for (int j = 0; j < 8; ++j)
                a[j] = fmaf(rp[j], conv_w[(d0 + j) * 4 + t], a[j]);
        }
    }
    half8 h, lo;
    #pragma unroll
    for (int j = 0; j < 8; ++j) {
        float v = a[j];
        float s = v / (1.f + expf(-v));
        _Float16 hv = (_Float16)s;
        h[j] = hv;
        lo[j] = (_Float16)(s - (float)hv);
    }
    _Float16* dp = xcs2 + (size_t)row * 4096 + d0;
    *(half8*)dp = h;
    *(half8*)(dp + 2048) = lo;
}

__device__ __forceinline__ float softplusf(float x) {
    return (x > 20.f) ? x : log1pf(expf(x));
}

// ---------- chunked scan ----------
__global__ __launch_bounds__(256) void scan_pass1(
    const float* __restrict__ dbu, const float* __restrict__ W_dt,
    const float* __restrict__ b_dt, const float* __restrict__ A_log,
    float* __restrict__ Sout, float* __restrict__ Pout)
{
    const int D = 2048, L = 1024, NDBU = 2080;
    const int g = blockIdx.x & 7;
    const int c = (blockIdx.x >> 3) & (NCHUNK - 1);
    const int b = blockIdx.x >> 8;
    const int d = g * 256 + threadIdx.x;

    float wdt[NSTATE], Aneg[NSTATE], s[NSTATE], P[NSTATE];
    #pragma unroll
    for (int n = 0; n < NSTATE; ++n) {
        wdt[n] = W_dt[d * NSTATE + n];
        Aneg[n] = -expf(A_log[d * NSTATE + n]);
        s[n] = 0.f; P[n] = 1.f;
    }
    const float bdt = b_dt[d];

    __shared__ float sbuf[LCHUNK][33];
    {
        int r = threadIdx.x >> 3;
        int c4 = (threadIdx.x & 7) * 4;
        float4 v = *(const float4*)(dbu + ((size_t)b * L + c * LCHUNK + r) * NDBU + c4);
        sbuf[r][c4 + 0] = v.x; sbuf[r][c4 + 1] = v.y;
        sbuf[r][c4 + 2] = v.z; sbuf[r][c4 + 3] = v.w;
    }
    __syncthreads();

    for (int li = 0; li < LCHUNK; ++li) {
        const int l = c * LCHUNK + li;
        const float u = dbu[((size_t)b * L + l) * NDBU + 32 + d];
        float accd = bdt;
        #pragma unroll
        for (int n = 0; n < NSTATE; ++n) accd = fmaf(sbuf[li][n], wdt[n], accd);
        const float delta = softplusf(accd);
        const float du = delta * u;
        #pragma unroll
        for (int n = 0; n < NSTATE; ++n) {
            float dA = expf(delta * Aneg[n]);
            s[n] = fmaf(dA, s[n], du * sbuf[li][16 + n]);
            P[n] *= dA;
        }
    }
    const size_t o = (((size_t)b * NCHUNK + c) * D + d) * NSTATE;
    #pragma unroll
    for (int n = 0; n < NSTATE; ++n) { Sout[o + n] = s[n]; Pout[o + n] = P[n]; }
}

__global__ __launch_bounds__(256) void scan_mid(
    const float* __restrict__ S, float* __restrict__ P)
{
    const int D = 2048;
    int idx = blockIdx.x * 256 + threadIdx.x;
    int n = idx & 15;
    int d = (idx >> 4) & (D - 1);
    int b = idx >> 15;
    float carry = 0.f;
    for (int c = 0; c < NCHUNK; ++c) {
        size_t o = (((size_t)b * NCHUNK + c) * D + d) * NSTATE + n;
        float Sv = S[o], Pv = P[o];
        P[o] = carry;
        carry = fmaf(Pv, carry, Sv);
    }
}

__global__ __launch_bounds__(256) void scan_pass2(
    const float* __restrict__ dbu, const float* __restrict__ z,
    const float* __restrict__ W_dt, const float* __restrict__ b_dt,
    const float* __restrict__ A_log, const float* __restrict__ Dp,
    const float* __restrict__ CarryIn, _Float16* __restrict__ y2)
{
    const int D = 2048, L = 1024, NDBU = 2080;
    const int g = blockIdx.x & 7;
    const int c = (blockIdx.x >> 3) & (NCHUNK - 1);
    const int b = blockIdx.x >> 8;
    const int d = g * 256 + threadIdx.x;

    float wdt[NSTATE], Aneg[NSTATE], s[NSTATE];
    const size_t o = (((size_t)b * NCHUNK + c) * D + d) * NSTATE;
    #pragma unroll
    for (int n = 0; n < NSTATE; ++n) {
        wdt[n] = W_dt[d * NSTATE + n];
        Aneg[n] = -expf(A_log[d * NSTATE + n]);
        s[n] = CarryIn[o + n];
    }
    const float bdt = b_dt[d];
    const float dp = Dp[d];

    __shared__ float sbuf[LCHUNK][33];
    {
        int r = threadIdx.x >> 3;
        int c4 = (threadIdx.x & 7) * 4;
        float4 v = *(const float4*)(dbu + ((size_t)b * L + c * LCHUNK + r) * NDBU + c4);
        sbuf[r][c4 + 0] = v.x; sbuf[r][c4 + 1] = v.y;
        sbuf[r][c4 + 2] = v.z; sbuf[r][c4 + 3] = v.w;
    }
    __syncthreads();

    for (int li = 0; li < LCHUNK; ++li) {
        const int l = c * LCHUNK + li;
        const int row = b * L + l;
        const float u = dbu[(size_t)row * NDBU + 32 + d];
        float accd = bdt;
        #pragma unroll
        for (int n = 0; n < NSTATE; ++n) accd = fmaf(sbuf[li][n], wdt[n], accd);
        const float delta = softplusf(accd);
        const float du = delta * u;
        float sum = 0.f;
        #pragma unroll
        for (int n = 0; n < NSTATE; ++n) {
            float dA = expf(delta * Aneg[n]);
            s[n] = fmaf(dA, s[n], du * sbuf[li][16 + n]);
            sum += s[n];
        }
        const float zz = z[(size_t)row * D + d];
        const float yv = (sum + u) * dp * (zz / (1.f + expf(-zz)));
        _Float16 hv = (_Float16)yv;
        y2[(size_t)row * 4096 + d] = hv;
        y2[(size_t)row * 4096 + 2048 + d] = (_Float16)(yv - (float)hv);
    }
}

// ---------- combine split-K partials + bias ----------
__global__ __launch_bounds__(256) void combine2(
    const float* __restrict__ p1, const float* __restrict__ p2,
    const float* __restrict__ bias, float* __restrict__ out)
{
    int i = (blockIdx.x * 256 + threadIdx.x) * 4;
    int n = i & 1023;
    float4 a = *(const float4*)(p1 + i);
    float4 b = *(const float4*)(p2 + i);
    float4 bb = *(const float4*)(bias + n);
    float4 r;
    r.x = a.x + b.x + bb.x; r.y = a.y + b.y + bb.y;
    r.z = a.z + b.z + bb.z; r.w = a.w + b.w + bb.w;
    *(float4*)(out + i) = r;
}

extern "C" void kernel_launch(void* const* d_in, const int* in_sizes, int n_in,
                              void* d_out, int out_size, void* d_ws, size_t ws_size,
                              hipStream_t stream) {
    const float* x      = (const float*)d_in[0];
    const float* W_in   = (const float*)d_in[1];
    const float* b_in   = (const float*)d_in[2];
    const float* conv_w = (const float*)d_in[3];
    const float* conv_b = (const float*)d_in[4];
    const float* W_x    = (const float*)d_in[5];
    const float* b_x    = (const float*)d_in[6];
    const float* W_dt   = (const float*)d_in[7];
    const float* b_dt   = (const float*)d_in[8];
    const float* A_log  = (const float*)d_in[9];
    const float* Dp     = (const float*)d_in[10];
    const float* W_out  = (const float*)d_in[11];
    const float* b_out  = (const float*)d_in[12];
    float* out = (float*)d_out;

    // ws regions (bytes):
    //  z    @ 0         : fp32 2048x2048                (16,777,216)
    //  xc/dbu @16777216 : fp32 2048x2048 then 2048x2080 (17,039,360)
    //  big  @33816576   : f16  16,777,216 B  {Win2 | xcs2 | y2}
    //  aux  @50593792   : 17,825,792 B       {xh2 | Wx2 | S | partials}
    //  misc @68419584   : 8,388,608 B        {P | Wout2}
    char* ws = (char*)d_ws;
    float*    z     = (float*)(ws);
    float*    xc    = (float*)(ws + 16777216);
    float*    dbu   = xc;
    _Float16* big   = (_Float16*)(ws + 33816576);
    _Float16* aux   = (_Float16*)(ws + 50593792);
    _Float16* misc  = (_Float16*)(ws + 68419584);

    _Float16* Win2  = big;                 // [4096][2048]
    _Float16* xh2   = aux;                 // [2048][2048]
    _Float16* xcs2  = big;                 // [2048][4096]
    _Float16* Wx2   = aux;                 // [2176][4096]
    float*    Sb    = (float*)aux;         // 2*32*2048*16
    float*    Pb    = (float*)misc;
    _Float16* y2    = big;                 // [2048][4096]
    _Float16* Wout2 = misc;                // [1024][4096]
    float*    part1 = (float*)aux;         // [2048][1024]
    float*    part2 = part1 + (size_t)2048 * 1024;

    dim3 blk(256);

    // converters for GEMM1
    convert_split<<<1024, blk, 0, stream>>>(x, xh2, 2048, 2048, 1024);
    convert_split<<<2048, blk, 0, stream>>>(W_in, Win2, 4096, 4096, 1024);

    // GEMM1: xz = x @ W_in.T + b_in -> xc (cols<2048) and z (cols>=2048)
    hgemm3<<<dim3(32, 16, 1), blk, 0, stream>>>(
        xh2, Win2, b_in, xc, z, 2048, 2048, 4096, 1024, 32, 0, 0);

    // conv + silu -> xcs2 (f16 hi|lo)
    conv_silu2<<<2048, blk, 0, stream>>>(xc, conv_w, conv_b, xcs2);

    // GEMM2: dbu = xcs @ W_x.T + b_x
    convert_split<<<2176, blk, 0, stream>>>(W_x, Wx2, 2080, 2176, 2048);
    hgemm3<<<dim3(17, 16, 1), blk, 0, stream>>>(
        xcs2, Wx2, b_x, dbu, (float*)nullptr, 1 << 30, 2080, 2080, 2048, 64, 0, 0);

    // chunked scan -> y2 (f16 hi|lo)
    scan_pass1<<<2 * NCHUNK * 8, blk, 0, stream>>>(dbu, W_dt, b_dt, A_log, Sb, Pb);
    scan_mid<<<(2 * 2048 * NSTATE) / 256, blk, 0, stream>>>(Sb, Pb);
    scan_pass2<<<2 * NCHUNK * 8, blk, 0, stream>>>(dbu, z, W_dt, b_dt, A_log, Dp, Pb, y2);

    // GEMM3 (split-K=2, one launch): out = y @ W_out.T + b_out
    convert_split<<<1024, blk, 0, stream>>>(W_out, Wout2, 1024, 1024, 2048);
    hgemm3<<<dim3(8, 16, 2), blk, 0, stream>>>(
        y2, Wout2, (const float*)nullptr, part1, (float*)nullptr, 1 << 30,
        1024, 1024, 2048, 32, 1024, (size_t)2048 * 1024);
    combine2<<<2048, blk, 0, stream>>>(part1, part2, b_out, out);
}

// Round 8
// 433.844 us; speedup vs baseline: 1.0667x; 1.0667x over previous
//
#include <hip/hip_runtime.h>
#include <math.h>

// Mamba block. GEMMs: f16 split-2 ([hi|lo] planes), 256x256 block tile,
// 512 threads / 8 waves (2Mx4N), wave tile 128x64 (MFMA:ds_read = 4:1),
// 2x64KB LDS double-buffer, global_load_lds staging, counted vmcnt(8),
// source+read XOR swizzle. Chunked parallel scan, fused conv/silu.

typedef _Float16 half8 __attribute__((ext_vector_type(8)));
typedef float floatx4 __attribute__((ext_vector_type(4)));

#define NSTATE 16
#define NCHUNK 32
#define LCHUNK 32

__device__ __forceinline__ void gload_lds16(const _Float16* g, _Float16* l) {
    __builtin_amdgcn_global_load_lds(
        (const __attribute__((address_space(1))) unsigned int*)g,
        (__attribute__((address_space(3))) unsigned int*)l, 16, 0, 0);
}

// ---------- converter: fp32 [R][K] -> f16 [Rpad][2K] = [hi | lo] ----------
__global__ __launch_bounds__(256) void convert_split(
    const float* __restrict__ src, _Float16* __restrict__ dst,
    int R, int Rpad, int K)
{
    int idx = blockIdx.x * 256 + threadIdx.x;
    int nck = K >> 3;
    int r = idx / nck;
    int g = idx - r * nck;
    if (r >= Rpad) return;
    half8 h, l;
    if (r < R) {
        const float* sp = src + (size_t)r * K + g * 8;
        #pragma unroll
        for (int e = 0; e < 8; ++e) {
            float x = sp[e];
            _Float16 hv = (_Float16)x;
            h[e] = hv;
            l[e] = (_Float16)(x - (float)hv);
        }
    } else {
        #pragma unroll
        for (int e = 0; e < 8; ++e) { h[e] = (_Float16)0.f; l[e] = (_Float16)0.f; }
    }
    _Float16* dp = dst + (size_t)r * 2 * K + g * 8;
    *(half8*)dp = h;
    *(half8*)(dp + K) = l;
}

// ---------- MFMA GEMM: C[M,N](fp32) = A2[M,2K](f16 hi|lo) @ W2[Npad,2K]^T ----
// Block 256x256, 8 waves (wm=wid>>2, wn=wid&3), wave tile 128x64. BK=32 pairs.
// LDS buffer (64KB): Ah[256][32] | Al[256][32] | Wh[256][32] | Wl[256][32].
// Staging: wave-pair p=wid>>1 stages plane p (8 x gload_lds16 per thread).
// Loop: vmcnt(8); barrier; compute; barrier; stage(k+2)->buf[k&1].
__device__ __forceinline__ void stage_tile(const _Float16* g, _Float16* dst, size_t K2) {
    #pragma unroll
    for (int j = 0; j < 8; ++j)
        gload_lds16(g + (size_t)j * 32 * K2, dst + j * 1024);
}

__global__ __launch_bounds__(512, 2) void hgemm4(
    const _Float16* __restrict__ A2, const _Float16* __restrict__ W2,
    const float* __restrict__ bias, float* __restrict__ C, float* __restrict__ C2,
    int colSplit, int ldc, int Nvalid, int K, int kSteps,
    int kzStride, size_t zStrideC)
{
    __shared__ _Float16 lds[2 * 32768];   // 128 KB

    // XCD-chunked block swizzle (nwg % 8 == 0)
    const int nbx = gridDim.x;
    const int h = blockIdx.y * nbx + blockIdx.x;
    const int nwg = nbx * gridDim.y;
    const int cpx = nwg >> 3;
    const int e = (h & 7) * cpx + (h >> 3);
    const int by = e / nbx, bx = e - by * nbx;

    const int tid = threadIdx.x;
    const int lane = tid & 63;
    const int wid = tid >> 6;
    const int wm = wid >> 2, wn = wid & 3;       // compute role
    const int m0 = by * 256, n0 = bx * 256;
    const int kg = lane >> 4, fr = lane & 15;
    const size_t K2 = (size_t)2 * K;
    const int kBegin = blockIdx.z * kzStride;

    // staging role: plane p (0:Ah 1:Al 2:Wh 3:Wl), wave-in-plane wip
    const int p = wid >> 1, wip = wid & 1;
    const bool isA = p < 2;
    const int scol = (((lane & 3) ^ ((lane >> 3) & 3)) << 3);  // source swizzle
    const _Float16* gbase = isA ? A2 + (size_t)(m0 + wip * 16 + (lane >> 2)) * K2
                                : W2 + (size_t)(n0 + wip * 16 + (lane >> 2)) * K2;
    const _Float16* gp = gbase + (p & 1) * K + kBegin + scol;
    const int dstOff = p * 8192 + wip * 512;     // halfs

    floatx4 acc[8][4];
    #pragma unroll
    for (int mi = 0; mi < 8; ++mi)
        #pragma unroll
        for (int ni = 0; ni < 4; ++ni)
            acc[mi][ni] = (floatx4){0.f, 0.f, 0.f, 0.f};

    const int rsw = (fr >> 1) & 3;               // read-side swizzle key

    // prologue: tile0 -> buf0, tile1 -> buf1 (16 loads in flight)
    stage_tile(gp, lds + dstOff, K2);
    stage_tile(gp + 32, lds + 32768 + dstOff, K2);

    for (int ks = 0; ks < kSteps; ++ks) {
        asm volatile("s_waitcnt vmcnt(8)" ::: "memory");  // my tile-ks loads done
        __builtin_amdgcn_s_barrier();                     // all waves' done
        __builtin_amdgcn_sched_barrier(0);

        const _Float16* buf = lds + (ks & 1) * 32768;
        half8 wh[4], wl[4];
        #pragma unroll
        for (int ni = 0; ni < 4; ++ni) {
            int off = (wn * 64 + ni * 16 + fr) * 32 + ((kg ^ rsw) << 3);
            wh[ni] = *(const half8*)(buf + 16384 + off);
            wl[ni] = *(const half8*)(buf + 24576 + off);
        }
        #pragma unroll
        for (int mh = 0; mh < 2; ++mh) {
            half8 ah[4], al[4];
            #pragma unroll
            for (int q = 0; q < 4; ++q) {
                int off = (wm * 128 + (mh * 4 + q) * 16 + fr) * 32 + ((kg ^ rsw) << 3);
                ah[q] = *(const half8*)(buf + off);
                al[q] = *(const half8*)(buf + 8192 + off);
            }
            #pragma unroll
            for (int q = 0; q < 4; ++q)
                #pragma unroll
                for (int ni = 0; ni < 4; ++ni) {
                    floatx4 a = acc[mh * 4 + q][ni];
                    a = __builtin_amdgcn_mfma_f32_16x16x32_f16(ah[q], wh[ni], a, 0, 0, 0);
                    a = __builtin_amdgcn_mfma_f32_16x16x32_f16(ah[q], wl[ni], a, 0, 0, 0);
                    a = __builtin_amdgcn_mfma_f32_16x16x32_f16(al[q], wh[ni], a, 0, 0, 0);
                    acc[mh * 4 + q][ni] = a;
                }
        }

        __builtin_amdgcn_s_barrier();             // all waves done reading buf[ks&1]
        __builtin_amdgcn_sched_barrier(0);
        int kt = ks + 2; if (kt > kSteps - 1) kt = kSteps - 1;   // clamp (uniform vmcnt)
        stage_tile(gp + (size_t)kt * 32, lds + (ks & 1) * 32768 + dstOff, K2);
    }

    asm volatile("s_waitcnt vmcnt(0)" ::: "memory");  // drain DMA before exit

    // epilogue: col = fr, row-in-frag = kg*4 + r
    float* Cz = C + blockIdx.z * zStrideC;
    #pragma unroll
    for (int ni = 0; ni < 4; ++ni) {
        int nn = n0 + wn * 64 + ni * 16 + fr;
        if (nn >= Nvalid) continue;
        float bv = bias ? bias[nn] : 0.f;
        float* Cp = Cz;
        int col = nn;
        if (C2 && nn >= colSplit) { Cp = C2; col = nn - colSplit; }
        #pragma unroll
        for (int mi = 0; mi < 8; ++mi) {
            int mm = m0 + wm * 128 + mi * 16 + kg * 4;
            float* ptr = Cp + (size_t)mm * ldc + col;
            #pragma unroll
            for (int r = 0; r < 4; ++r)
                ptr[(size_t)r * ldc] = acc[mi][ni][r] + bv;
        }
    }
}

// ---------- conv + silu, emits f16 [hi|lo] layout (width 2*2048) ----------
__global__ __launch_bounds__(256) void conv_silu2(
    const float* __restrict__ xc, const float* __restrict__ conv_w,
    const float* __restrict__ conv_b, _Float16* __restrict__ xcs2)
{
    const int D = 2048, L = 1024;
    int idx = blockIdx.x * 256 + threadIdx.x;
    int g = idx & 255;
    int l = (idx >> 8) & (L - 1);
    int b = idx >> 18;
    int d0 = g * 8;
    int row = b * L + l;

    float a[8];
    #pragma unroll
    for (int j = 0; j < 8; ++j) a[j] = conv_b[d0 + j];
    #pragma unroll
    for (int t = 0; t < 4; ++t) {
        int lt = l - 3 + t;
        if (lt >= 0) {
            const float* rp = xc + (size_t)(b * L + lt) * D + d0;
            #pragma unroll
            for (int j = 0; j < 8; ++j)
                a[j] = fmaf(rp[j], conv_w[(d0 + j) * 4 + t], a[j]);
        }
    }
    half8 h, lo;
    #pragma unroll
    for (int j = 0; j < 8; ++j) {
        float v = a[j];
        float s = v / (1.f + expf(-v));
        _Float16 hv = (_Float16)s;
        h[j] = hv;
        lo[j] = (_Float16)(s - (float)hv);
    }
    _Float16* dp = xcs2 + (size_t)row * 4096 + d0;
    *(half8*)dp = h;
    *(half8*)(dp + 2048) = lo;
}

__device__ __forceinline__ float softplusf(float x) {
    return (x > 20.f) ? x : log1pf(expf(x));
}

// ---------- chunked scan ----------
__global__ __launch_bounds__(256) void scan_pass1(
    const float* __restrict__ dbu, const float* __restrict__ W_dt,
    const float* __restrict__ b_dt, const float* __restrict__ A_log,
    float* __restrict__ Sout, float* __restrict__ Pout)
{
    const int D = 2048, L = 1024, NDBU = 2080;
    const int g = blockIdx.x & 7;
    const int c = (blockIdx.x >> 3) & (NCHUNK - 1);
    const int b = blockIdx.x >> 8;
    const int d = g * 256 + threadIdx.x;

    float wdt[NSTATE], Aneg[NSTATE], s[NSTATE], P[NSTATE];
    #pragma unroll
    for (int n = 0; n < NSTATE; ++n) {
        wdt[n] = W_dt[d * NSTATE + n];
        Aneg[n] = -expf(A_log[d * NSTATE + n]);
        s[n] = 0.f; P[n] = 1.f;
    }
    const float bdt = b_dt[d];

    __shared__ float sbuf[LCHUNK][33];
    {
        int r = threadIdx.x >> 3;
        int c4 = (threadIdx.x & 7) * 4;
        float4 v = *(const float4*)(dbu + ((size_t)b * L + c * LCHUNK + r) * NDBU + c4);
        sbuf[r][c4 + 0] = v.x; sbuf[r][c4 + 1] = v.y;
        sbuf[r][c4 + 2] = v.z; sbuf[r][c4 + 3] = v.w;
    }
    __syncthreads();

    for (int li = 0; li < LCHUNK; ++li) {
        const int l = c * LCHUNK + li;
        const float u = dbu[((size_t)b * L + l) * NDBU + 32 + d];
        float accd = bdt;
        #pragma unroll
        for (int n = 0; n < NSTATE; ++n) accd = fmaf(sbuf[li][n], wdt[n], accd);
        const float delta = softplusf(accd);
        const float du = delta * u;
        #pragma unroll
        for (int n = 0; n < NSTATE; ++n) {
            float dA = expf(delta * Aneg[n]);
            s[n] = fmaf(dA, s[n], du * sbuf[li][16 + n]);
            P[n] *= dA;
        }
    }
    const size_t o = (((size_t)b * NCHUNK + c) * D + d) * NSTATE;
    #pragma unroll
    for (int n = 0; n < NSTATE; ++n) { Sout[o + n] = s[n]; Pout[o + n] = P[n]; }
}

__global__ __launch_bounds__(256) void scan_mid(
    const float* __restrict__ S, float* __restrict__ P)
{
    const int D = 2048;
    int idx = blockIdx.x * 256 + threadIdx.x;
    int n = idx & 15;
    int d = (idx >> 4) & (D - 1);
    int b = idx >> 15;
    float carry = 0.f;
    for (int c = 0; c < NCHUNK; ++c) {
        size_t o = (((size_t)b * NCHUNK + c) * D + d) * NSTATE + n;
        float Sv = S[o], Pv = P[o];
        P[o] = carry;
        carry = fmaf(Pv, carry, Sv);
    }
}

__global__ __launch_bounds__(256) void scan_pass2(
    const float* __restrict__ dbu, const float* __restrict__ z,
    const float* __restrict__ W_dt, const float* __restrict__ b_dt,
    const float* __restrict__ A_log, const float* __restrict__ Dp,
    const float* __restrict__ CarryIn, _Float16* __restrict__ y2)
{
    const int D = 2048, L = 1024, NDBU = 2080;
    const int g = blockIdx.x & 7;
    const int c = (blockIdx.x >> 3) & (NCHUNK - 1);
    const int b = blockIdx.x >> 8;
    const int d = g * 256 + threadIdx.x;

    float wdt[NSTATE], Aneg[NSTATE], s[NSTATE];
    const size_t o = (((size_t)b * NCHUNK + c) * D + d) * NSTATE;
    #pragma unroll
    for (int n = 0; n < NSTATE; ++n) {
        wdt[n] = W_dt[d * NSTATE + n];
        Aneg[n] = -expf(A_log[d * NSTATE + n]);
        s[n] = CarryIn[o + n];
    }
    const float bdt = b_dt[d];
    const float dp = Dp[d];

    __shared__ float sbuf[LCHUNK][33];
    {
        int r = threadIdx.x >> 3;
        int c4 = (threadIdx.x & 7) * 4;
        float4 v = *(const float4*)(dbu + ((size_t)b * L + c * LCHUNK + r) * NDBU + c4);
        sbuf[r][c4 + 0] = v.x; sbuf[r][c4 + 1] = v.y;
        sbuf[r][c4 + 2] = v.z; sbuf[r][c4 + 3] = v.w;
    }
    __syncthreads();

    for (int li = 0; li < LCHUNK; ++li) {
        const int l = c * LCHUNK + li;
        const int row = b * L + l;
        const float u = dbu[(size_t)row * NDBU + 32 + d];
        float accd = bdt;
        #pragma unroll
        for (int n = 0; n < NSTATE; ++n) accd = fmaf(sbuf[li][n], wdt[n], accd);
        const float delta = softplusf(accd);
        const float du = delta * u;
        float sum = 0.f;
        #pragma unroll
        for (int n = 0; n < NSTATE; ++n) {
            float dA = expf(delta * Aneg[n]);
            s[n] = fmaf(dA, s[n], du * sbuf[li][16 + n]);
            sum += s[n];
        }
        const float zz = z[(size_t)row * D + d];
        const float yv = (sum + u) * dp * (zz / (1.f + expf(-zz)));
        _Float16 hv = (_Float16)yv;
        y2[(size_t)row * 4096 + d] = hv;
        y2[(size_t)row * 4096 + 2048 + d] = (_Float16)(yv - (float)hv);
    }
}

// ---------- combine 4 split-K partials + bias ----------
__global__ __launch_bounds__(256) void combine4(
    const float* __restrict__ parts, const float* __restrict__ bias,
    float* __restrict__ out)
{
    const size_t PS = (size_t)2048 * 1024;
    int i = (blockIdx.x * 256 + threadIdx.x) * 4;
    int n = i & 1023;
    float4 a = *(const float4*)(parts + i);
    float4 b = *(const float4*)(parts + PS + i);
    float4 cc = *(const float4*)(parts + 2 * PS + i);
    float4 dd = *(const float4*)(parts + 3 * PS + i);
    float4 bb = *(const float4*)(bias + n);
    float4 r;
    r.x = a.x + b.x + cc.x + dd.x + bb.x;
    r.y = a.y + b.y + cc.y + dd.y + bb.y;
    r.z = a.z + b.z + cc.z + dd.z + bb.z;
    r.w = a.w + b.w + cc.w + dd.w + bb.w;
    *(float4*)(out + i) = r;
}

extern "C" void kernel_launch(void* const* d_in, const int* in_sizes, int n_in,
                              void* d_out, int out_size, void* d_ws, size_t ws_size,
                              hipStream_t stream) {
    const float* x      = (const float*)d_in[0];
    const float* W_in   = (const float*)d_in[1];
    const float* b_in   = (const float*)d_in[2];
    const float* conv_w = (const float*)d_in[3];
    const float* conv_b = (const float*)d_in[4];
    const float* W_x    = (const float*)d_in[5];
    const float* b_x    = (const float*)d_in[6];
    const float* W_dt   = (const float*)d_in[7];
    const float* b_dt   = (const float*)d_in[8];
    const float* A_log  = (const float*)d_in[9];
    const float* Dp     = (const float*)d_in[10];
    const float* W_out  = (const float*)d_in[11];
    const float* b_out  = (const float*)d_in[12];
    float* out = (float*)d_out;

    // ws (bytes), high-water 77.9MB (R1 proved >=81MB):
    //  z     @ 0         : fp32 [2048][2048] (16MB); later GEMM3 parts (32MB @0)
    //  xc/dbu@ 16777216  : fp32 [2048][2080] (17.04MB)
    //  big   @ 33816576  : f16 16MB {Win2 -> xcs2 -> y2}
    //  aux   @ 50593792  : f16 Wx2 [2304][4096] (18.87MB); later S(8MB)+P(8MB)
    //  whi   @ 69468160  : f16 8MB {xh2 -> Wout2}
    char* ws = (char*)d_ws;
    float*    z     = (float*)(ws);
    float*    xc    = (float*)(ws + 16777216);
    float*    dbu   = xc;
    _Float16* big   = (_Float16*)(ws + 33816576);
    _Float16* aux   = (_Float16*)(ws + 50593792);
    _Float16* whi   = (_Float16*)(ws + 69468160);

    _Float16* Win2  = big;                 // [4096][2048]
    _Float16* xh2   = whi;                 // [2048][2048]
    _Float16* xcs2  = big;                 // [2048][4096]
    _Float16* Wx2   = aux;                 // [2304][4096]
    float*    Sb    = (float*)aux;         // after GEMM2 (Wx2 dead)
    float*    Pb    = Sb + (size_t)2 * NCHUNK * 2048 * NSTATE;
    _Float16* y2    = big;                 // [2048][4096]
    _Float16* Wout2 = whi;                 // [1024][4096] (xh2 dead)
    float*    parts = (float*)ws;          // 4 x [2048][1024] (z/dbu dead)

    dim3 blk(256);
    dim3 blkG(512);

    // converters for GEMM1
    convert_split<<<1024, blk, 0, stream>>>(x, xh2, 2048, 2048, 1024);
    convert_split<<<2048, blk, 0, stream>>>(W_in, Win2, 4096, 4096, 1024);

    // GEMM1: xz = x @ W_in.T + b_in -> xc (cols<2048) and z (cols>=2048)
    hgemm4<<<dim3(16, 8, 1), blkG, 0, stream>>>(
        xh2, Win2, b_in, xc, z, 2048, 2048, 4096, 1024, 32, 0, 0);

    // conv + silu -> xcs2 (f16 hi|lo)
    conv_silu2<<<2048, blk, 0, stream>>>(xc, conv_w, conv_b, xcs2);

    // GEMM2: dbu = xcs @ W_x.T + b_x  (N padded to 2304)
    convert_split<<<2304, blk, 0, stream>>>(W_x, Wx2, 2080, 2304, 2048);
    hgemm4<<<dim3(9, 8, 1), blkG, 0, stream>>>(
        xcs2, Wx2, b_x, dbu, (float*)nullptr, 1 << 30, 2080, 2080, 2048, 64, 0, 0);

    // chunked scan -> y2 (f16 hi|lo)
    scan_pass1<<<2 * NCHUNK * 8, blk, 0, stream>>>(dbu, W_dt, b_dt, A_log, Sb, Pb);
    scan_mid<<<(2 * 2048 * NSTATE) / 256, blk, 0, stream>>>(Sb, Pb);
    scan_pass2<<<2 * NCHUNK * 8, blk, 0, stream>>>(dbu, z, W_dt, b_dt, A_log, Dp, Pb, y2);

    // GEMM3 (split-K=4): out = y @ W_out.T + b_out
    convert_split<<<1024, blk, 0, stream>>>(W_out, Wout2, 1024, 1024, 2048);
    hgemm4<<<dim3(4, 8, 4), blkG, 0, stream>>>(
        y2, Wout2, (const float*)nullptr, parts, (float*)nullptr, 1 << 30,
        1024, 1024, 2048, 16, 512, (size_t)2048 * 1024);
    combine4<<<2048, blk, 0, stream>>>(parts, b_out, out);
}

// Round 9
// 330.049 us; speedup vs baseline: 1.4021x; 1.3145x over previous
//
#include <hip/hip_runtime.h>
#include <math.h>

// Mamba block. GEMMs: f16 split-2 ([hi|lo] planes), templated MFMA GEMM
// (per-GEMM tile shape so grid >= 256 blocks), 2-buffer LDS ring with
// distance-2 global_load_lds prefetch, counted vmcnt (never 0 in-loop),
// source+read XOR swizzle, XCD block swizzle. Chunked parallel scan.

typedef _Float16 half8 __attribute__((ext_vector_type(8)));
typedef float floatx4 __attribute__((ext_vector_type(4)));

#define NSTATE 16
#define NCHUNK 32
#define LCHUNK 32

__device__ __forceinline__ void gload_lds16(const _Float16* g, _Float16* l) {
    __builtin_amdgcn_global_load_lds(
        (const __attribute__((address_space(1))) unsigned int*)g,
        (__attribute__((address_space(3))) unsigned int*)l, 16, 0, 0);
}

// ---------- converter: fp32 [R][K] -> f16 [Rpad][2K] = [hi | lo] ----------
__global__ __launch_bounds__(256) void convert_split(
    const float* __restrict__ src, _Float16* __restrict__ dst,
    int R, int Rpad, int K)
{
    int idx = blockIdx.x * 256 + threadIdx.x;
    int nck = K >> 3;
    int r = idx / nck;
    int g = idx - r * nck;
    if (r >= Rpad) return;
    half8 h, l;
    if (r < R) {
        const float* sp = src + (size_t)r * K + g * 8;
        #pragma unroll
        for (int e = 0; e < 8; ++e) {
            float x = sp[e];
            _Float16 hv = (_Float16)x;
            h[e] = hv;
            l[e] = (_Float16)(x - (float)hv);
        }
    } else {
        #pragma unroll
        for (int e = 0; e < 8; ++e) { h[e] = (_Float16)0.f; l[e] = (_Float16)0.f; }
    }
    _Float16* dp = dst + (size_t)r * 2 * K + g * 8;
    *(half8*)dp = h;
    *(half8*)(dp + K) = l;
}

// ---------- MFMA GEMM: C[M,N](fp32) = A2[M,2K](f16 hi|lo) @ W2[Npad,2K]^T ----
// Block BM x BN, WAVES waves (WGM x WGN), wave tile 64x64, BK=32 pairs.
// LDS buffer: Ah[BM][32] | Al[BM][32] | Wh[BN][32] | Wl[BN][32], 2 buffers.
// Each wave stages NLOADS = (BM+BN)*8/(WAVES*64) chunk-groups per K-step.
// Loop: vmcnt(NLOADS); barrier; compute; barrier; stage(k+2)->buf[k&1].
template<int BM, int BN, int WGN, int WAVES, int NLOADS>
__global__ __launch_bounds__(WAVES * 64, 2) void hgemmT(
    const _Float16* __restrict__ A2, const _Float16* __restrict__ W2,
    const float* __restrict__ bias, float* __restrict__ C, float* __restrict__ C2,
    int colSplit, int ldc, int Nvalid, int K, int kSteps,
    int kzStride, size_t zStrideC)
{
    constexpr int BUFH = (BM + BN) * 64;   // halfs per buffer
    __shared__ _Float16 lds[2 * BUFH];

    // XCD-chunked bijective block swizzle (nwg % 8 == 0)
    const int nbx = gridDim.x;
    const int h = blockIdx.y * nbx + blockIdx.x;
    const int nwg = nbx * gridDim.y;
    const int cpx = nwg >> 3;
    const int e = (h & 7) * cpx + (h >> 3);
    const int by = e / nbx, bx = e - by * nbx;

    const int tid = threadIdx.x;
    const int lane = tid & 63;
    const int wid = tid >> 6;
    const int wm = wid / WGN, wn = wid % WGN;
    const int m0 = by * BM, n0 = bx * BN;
    const int kg = lane >> 4, fr = lane & 15;
    const size_t K2 = (size_t)2 * K;
    const int kBegin = blockIdx.z * kzStride;

    // staging plan: thread covers chunks c = (wid*NLOADS + j)*64 + lane
    // planes (in 16B chunks): Ah [0,4BM) | Al [4BM,8BM) | Wh [..,+4BN) | Wl
    const _Float16* src[NLOADS];
    int dstH[NLOADS];
    #pragma unroll
    for (int j = 0; j < NLOADS; ++j) {
        int c = (wid * NLOADS + j) * 64 + lane;
        int isa, limb, pr;
        if (c < 4 * BM)                    { isa = 1; limb = 0; pr = c; }
        else if (c < 8 * BM)               { isa = 1; limb = 1; pr = c - 4 * BM; }
        else if (c < 8 * BM + 4 * BN)      { isa = 0; limb = 0; pr = c - 8 * BM; }
        else                               { isa = 0; limb = 1; pr = c - 8 * BM - 4 * BN; }
        int row = pr >> 2, cc = pr & 3;
        int sw = (row >> 1) & 3;                       // source XOR swizzle
        const _Float16* base = isa ? A2 + (size_t)(m0 + row) * K2
                                   : W2 + (size_t)(n0 + row) * K2;
        src[j] = base + (size_t)limb * K + kBegin + ((cc ^ sw) << 3);
        dstH[j] = (wid * NLOADS + j) * 512;            // wave-uniform base
    }

    floatx4 acc[4][4];
    #pragma unroll
    for (int mi = 0; mi < 4; ++mi)
        #pragma unroll
        for (int ni = 0; ni < 4; ++ni)
            acc[mi][ni] = (floatx4){0.f, 0.f, 0.f, 0.f};

    const int ksw = (kg ^ ((fr >> 1) & 3)) << 3;       // read-side swizzle

    // prologue: tile0 -> buf0, tile1 -> buf1
    #pragma unroll
    for (int j = 0; j < NLOADS; ++j)
        gload_lds16(src[j], lds + dstH[j]);
    #pragma unroll
    for (int j = 0; j < NLOADS; ++j)
        gload_lds16(src[j] + 32, lds + BUFH + dstH[j]);

    for (int ks = 0; ks < kSteps; ++ks) {
        if constexpr (NLOADS == 6)
            asm volatile("s_waitcnt vmcnt(6)" ::: "memory");
        else
            asm volatile("s_waitcnt vmcnt(8)" ::: "memory");
        __builtin_amdgcn_s_barrier();
        __builtin_amdgcn_sched_barrier(0);

        const _Float16* buf = lds + (ks & 1) * BUFH;
        half8 ah[4], al[4], wh[4], wl[4];
        #pragma unroll
        for (int ni = 0; ni < 4; ++ni) {
            int off = 2 * BM * 32 + (wn * 64 + ni * 16 + fr) * 32 + ksw;
            wh[ni] = *(const half8*)(buf + off);
            wl[ni] = *(const half8*)(buf + BN * 32 + off);
        }
        #pragma unroll
        for (int mi = 0; mi < 4; ++mi) {
            int off = (wm * 64 + mi * 16 + fr) * 32 + ksw;
            ah[mi] = *(const half8*)(buf + off);
            al[mi] = *(const half8*)(buf + BM * 32 + off);
        }
        #pragma unroll
        for (int mi = 0; mi < 4; ++mi)
            #pragma unroll
            for (int ni = 0; ni < 4; ++ni) {
                floatx4 a = acc[mi][ni];
                a = __builtin_amdgcn_mfma_f32_16x16x32_f16(ah[mi], wh[ni], a, 0, 0, 0);
                a = __builtin_amdgcn_mfma_f32_16x16x32_f16(ah[mi], wl[ni], a, 0, 0, 0);
                a = __builtin_amdgcn_mfma_f32_16x16x32_f16(al[mi], wh[ni], a, 0, 0, 0);
                acc[mi][ni] = a;
            }

        __builtin_amdgcn_s_barrier();            // all waves done reading buf[ks&1]
        __builtin_amdgcn_sched_barrier(0);
        int kt = ks + 2; if (kt > kSteps - 1) kt = kSteps - 1;  // uniform vmcnt tail
        #pragma unroll
        for (int j = 0; j < NLOADS; ++j)
            gload_lds16(src[j] + (size_t)kt * 32, lds + (ks & 1) * BUFH + dstH[j]);
    }

    asm volatile("s_waitcnt vmcnt(0)" ::: "memory");  // drain DMA before exit

    // epilogue: col = fr, row-in-frag = kg*4 + r
    float* Cz = C + blockIdx.z * zStrideC;
    #pragma unroll
    for (int ni = 0; ni < 4; ++ni) {
        int nn = n0 + wn * 64 + ni * 16 + fr;
        if (nn >= Nvalid) continue;
        float bv = bias ? bias[nn] : 0.f;
        float* Cp = Cz;
        int col = nn;
        if (C2 && nn >= colSplit) { Cp = C2; col = nn - colSplit; }
        #pragma unroll
        for (int mi = 0; mi < 4; ++mi) {
            int mm = m0 + wm * 64 + mi * 16 + kg * 4;
            float* ptr = Cp + (size_t)mm * ldc + col;
            #pragma unroll
            for (int r = 0; r < 4; ++r)
                ptr[(size_t)r * ldc] = acc[mi][ni][r] + bv;
        }
    }
}

// ---------- conv + silu, emits f16 [hi|lo] layout (width 2*2048) ----------
__global__ __launch_bounds__(256) void conv_silu2(
    const float* __restrict__ xc, const float* __restrict__ conv_w,
    const float* __restrict__ conv_b, _Float16* __restrict__ xcs2)
{
    const int D = 2048, L = 1024;
    int idx = blockIdx.x * 256 + threadIdx.x;
    int g = idx & 255;
    int l = (idx >> 8) & (L - 1);
    int b = idx >> 18;
    int d0 = g * 8;
    int row = b * L + l;

    float a[8];
    #pragma unroll
    for (int j = 0; j < 8; ++j) a[j] = conv_b[d0 + j];
    #pragma unroll
    for (int t = 0; t < 4; ++t) {
        int lt = l - 3 + t;
        if (lt >= 0) {
            const float* rp = xc + (size_t)(b * L + lt) * D + d0;
            #pragma unroll
            for (int j = 0; j < 8; ++j)
                a[j] = fmaf(rp[j], conv_w[(d0 + j) * 4 + t], a[j]);
        }
    }
    half8 h, lo;
    #pragma unroll
    for (int j = 0; j < 8; ++j) {
        float v = a[j];
        float s = v / (1.f + expf(-v));
        _Float16 hv = (_Float16)s;
        h[j] = hv;
        lo[j] = (_Float16)(s - (float)hv);
    }
    _Float16* dp = xcs2 + (size_t)row * 4096 + d0;
    *(half8*)dp = h;
    *(half8*)(dp + 2048) = lo;
}

__device__ __forceinline__ float softplusf(float x) {
    return (x > 20.f) ? x : log1pf(expf(x));
}

// ---------- chunked scan ----------
__global__ __launch_bounds__(256) void scan_pass1(
    const float* __restrict__ dbu, const float* __restrict__ W_dt,
    const float* __restrict__ b_dt, const float* __restrict__ A_log,
    float* __restrict__ Sout, float* __restrict__ Pout)
{
    const int D = 2048, L = 1024, NDBU = 2080;
    const int g = blockIdx.x & 7;
    const int c = (blockIdx.x >> 3) & (NCHUNK - 1);
    const int b = blockIdx.x >> 8;
    const int d = g * 256 + threadIdx.x;

    float wdt[NSTATE], Aneg[NSTATE], s[NSTATE], P[NSTATE];
    #pragma unroll
    for (int n = 0; n < NSTATE; ++n) {
        wdt[n] = W_dt[d * NSTATE + n];
        Aneg[n] = -expf(A_log[d * NSTATE + n]);
        s[n] = 0.f; P[n] = 1.f;
    }
    const float bdt = b_dt[d];

    __shared__ float sbuf[LCHUNK][33];
    {
        int r = threadIdx.x >> 3;
        int c4 = (threadIdx.x & 7) * 4;
        float4 v = *(const float4*)(dbu + ((size_t)b * L + c * LCHUNK + r) * NDBU + c4);
        sbuf[r][c4 + 0] = v.x; sbuf[r][c4 + 1] = v.y;
        sbuf[r][c4 + 2] = v.z; sbuf[r][c4 + 3] = v.w;
    }
    __syncthreads();

    for (int li = 0; li < LCHUNK; ++li) {
        const int l = c * LCHUNK + li;
        const float u = dbu[((size_t)b * L + l) * NDBU + 32 + d];
        float accd = bdt;
        #pragma unroll
        for (int n = 0; n < NSTATE; ++n) accd = fmaf(sbuf[li][n], wdt[n], accd);
        const float delta = softplusf(accd);
        const float du = delta * u;
        #pragma unroll
        for (int n = 0; n < NSTATE; ++n) {
            float dA = expf(delta * Aneg[n]);
            s[n] = fmaf(dA, s[n], du * sbuf[li][16 + n]);
            P[n] *= dA;
        }
    }
    const size_t o = (((size_t)b * NCHUNK + c) * D + d) * NSTATE;
    #pragma unroll
    for (int n = 0; n < NSTATE; ++n) { Sout[o + n] = s[n]; Pout[o + n] = P[n]; }
}

__global__ __launch_bounds__(256) void scan_mid(
    const float* __restrict__ S, float* __restrict__ P)
{
    const int D = 2048;
    int idx = blockIdx.x * 256 + threadIdx.x;
    int n = idx & 15;
    int d = (idx >> 4) & (D - 1);
    int b = idx >> 15;
    float carry = 0.f;
    for (int c = 0; c < NCHUNK; ++c) {
        size_t o = (((size_t)b * NCHUNK + c) * D + d) * NSTATE + n;
        float Sv = S[o], Pv = P[o];
        P[o] = carry;
        carry = fmaf(Pv, carry, Sv);
    }
}

__global__ __launch_bounds__(256) void scan_pass2(
    const float* __restrict__ dbu, const float* __restrict__ z,
    const float* __restrict__ W_dt, const float* __restrict__ b_dt,
    const float* __restrict__ A_log, const float* __restrict__ Dp,
    const float* __restrict__ CarryIn, _Float16* __restrict__ y2)
{
    const int D = 2048, L = 1024, NDBU = 2080;
    const int g = blockIdx.x & 7;
    const int c = (blockIdx.x >> 3) & (NCHUNK - 1);
    const int b = blockIdx.x >> 8;
    const int d = g * 256 + threadIdx.x;

    float wdt[NSTATE], Aneg[NSTATE], s[NSTATE];
    const size_t o = (((size_t)b * NCHUNK + c) * D + d) * NSTATE;
    #pragma unroll
    for (int n = 0; n < NSTATE; ++n) {
        wdt[n] = W_dt[d * NSTATE + n];
        Aneg[n] = -expf(A_log[d * NSTATE + n]);
        s[n] = CarryIn[o + n];
    }
    const float bdt = b_dt[d];
    const float dp = Dp[d];

    __shared__ float sbuf[LCHUNK][33];
    {
        int r = threadIdx.x >> 3;
        int c4 = (threadIdx.x & 7) * 4;
        float4 v = *(const float4*)(dbu + ((size_t)b * L + c * LCHUNK + r) * NDBU + c4);
        sbuf[r][c4 + 0] = v.x; sbuf[r][c4 + 1] = v.y;
        sbuf[r][c4 + 2] = v.z; sbuf[r][c4 + 3] = v.w;
    }
    __syncthreads();

    for (int li = 0; li < LCHUNK; ++li) {
        const int l = c * LCHUNK + li;
        const int row = b * L + l;
        const float u = dbu[(size_t)row * NDBU + 32 + d];
        float accd = bdt;
        #pragma unroll
        for (int n = 0; n < NSTATE; ++n) accd = fmaf(sbuf[li][n], wdt[n], accd);
        const float delta = softplusf(accd);
        const float du = delta * u;
        float sum = 0.f;
        #pragma unroll
        for (int n = 0; n < NSTATE; ++n) {
            float dA = expf(delta * Aneg[n]);
            s[n] = fmaf(dA, s[n], du * sbuf[li][16 + n]);
            sum += s[n];
        }
        const float zz = z[(size_t)row * D + d];
        const float yv = (sum + u) * dp * (zz / (1.f + expf(-zz)));
        _Float16 hv = (_Float16)yv;
        y2[(size_t)row * 4096 + d] = hv;
        y2[(size_t)row * 4096 + 2048 + d] = (_Float16)(yv - (float)hv);
    }
}

// ---------- combine 2 split-K partials + bias ----------
__global__ __launch_bounds__(256) void combine2(
    const float* __restrict__ p1, const float* __restrict__ p2,
    const float* __restrict__ bias, float* __restrict__ out)
{
    int i = (blockIdx.x * 256 + threadIdx.x) * 4;
    int n = i & 1023;
    float4 a = *(const float4*)(p1 + i);
    float4 b = *(const float4*)(p2 + i);
    float4 bb = *(const float4*)(bias + n);
    float4 r;
    r.x = a.x + b.x + bb.x; r.y = a.y + b.y + bb.y;
    r.z = a.z + b.z + bb.z; r.w = a.w + b.w + bb.w;
    *(float4*)(out + i) = r;
}

extern "C" void kernel_launch(void* const* d_in, const int* in_sizes, int n_in,
                              void* d_out, int out_size, void* d_ws, size_t ws_size,
                              hipStream_t stream) {
    const float* x      = (const float*)d_in[0];
    const float* W_in   = (const float*)d_in[1];
    const float* b_in   = (const float*)d_in[2];
    const float* conv_w = (const float*)d_in[3];
    const float* conv_b = (const float*)d_in[4];
    const float* W_x    = (const float*)d_in[5];
    const float* b_x    = (const float*)d_in[6];
    const float* W_dt   = (const float*)d_in[7];
    const float* b_dt   = (const float*)d_in[8];
    const float* A_log  = (const float*)d_in[9];
    const float* Dp     = (const float*)d_in[10];
    const float* W_out  = (const float*)d_in[11];
    const float* b_out  = (const float*)d_in[12];
    float* out = (float*)d_out;

    // ws (bytes), high-water ~77.9MB (R1 proved >=84MB available):
    //  z/parts @ 0        : fp32 16.8MB (z), later 2x8.4MB split-K parts
    //  xc/dbu  @ 16777216 : fp32 [2048][2080] (17.04MB)
    //  big     @ 33816576 : f16 16.8MB {Win2 -> xcs2 -> y2}
    //  aux     @ 50593792 : f16 Wx2 [2176][4096] (17.8MB); later S(8MB)+P(8MB)
    //  whi     @ 69468160 : f16 8.4MB {xh2 -> Wout2}
    char* ws = (char*)d_ws;
    float*    z     = (float*)(ws);
    float*    xc    = (float*)(ws + 16777216);
    float*    dbu   = xc;
    _Float16* big   = (_Float16*)(ws + 33816576);
    _Float16* aux   = (_Float16*)(ws + 50593792);
    _Float16* whi   = (_Float16*)(ws + 69468160);

    _Float16* Win2  = big;                 // [4096][2048]
    _Float16* xh2   = whi;                 // [2048][2048]
    _Float16* xcs2  = big;                 // [2048][4096]
    _Float16* Wx2   = aux;                 // [2176][4096]
    float*    Sb    = (float*)aux;         // after GEMM2 (Wx2 dead)
    float*    Pb    = Sb + (size_t)2 * NCHUNK * 2048 * NSTATE;
    _Float16* y2    = big;                 // [2048][4096]
    _Float16* Wout2 = whi;                 // [1024][4096] (xh2 dead)
    float*    part1 = (float*)ws;          // 2 x [2048][1024] (z dead)
    float*    part2 = part1 + (size_t)2048 * 1024;

    dim3 blk(256);

    // converters for GEMM1
    convert_split<<<1024, blk, 0, stream>>>(x, xh2, 2048, 2048, 1024);
    convert_split<<<2048, blk, 0, stream>>>(W_in, Win2, 4096, 4096, 1024);

    // GEMM1: xz = x @ W_in.T + b_in -> xc (cols<2048) and z (cols>=2048)
    // BM=256, BN=128, 8 waves, grid 32x8 = 256 blocks
    hgemmT<256, 128, 2, 8, 6><<<dim3(32, 8, 1), dim3(512), 0, stream>>>(
        xh2, Win2, b_in, xc, z, 2048, 2048, 4096, 1024, 32, 0, 0);

    // conv + silu -> xcs2 (f16 hi|lo)
    conv_silu2<<<2048, blk, 0, stream>>>(xc, conv_w, conv_b, xcs2);

    // GEMM2: dbu = xcs @ W_x.T + b_x  (N padded to 2176; grid 17x16 = 272)
    convert_split<<<2176, blk, 0, stream>>>(W_x, Wx2, 2080, 2176, 2048);
    hgemmT<128, 128, 2, 4, 8><<<dim3(17, 16, 1), blk, 0, stream>>>(
        xcs2, Wx2, b_x, dbu, (float*)nullptr, 1 << 30, 2080, 2080, 2048, 64, 0, 0);

    // chunked scan -> y2 (f16 hi|lo)
    scan_pass1<<<2 * NCHUNK * 8, blk, 0, stream>>>(dbu, W_dt, b_dt, A_log, Sb, Pb);
    scan_mid<<<(2 * 2048 * NSTATE) / 256, blk, 0, stream>>>(Sb, Pb);
    scan_pass2<<<2 * NCHUNK * 8, blk, 0, stream>>>(dbu, z, W_dt, b_dt, A_log, Dp, Pb, y2);

    // GEMM3 (split-K=2): out = y @ W_out.T + b_out  (grid 8x16x2 = 256)
    convert_split<<<1024, blk, 0, stream>>>(W_out, Wout2, 1024, 1024, 2048);
    hgemmT<128, 128, 2, 4, 8><<<dim3(8, 16, 2), blk, 0, stream>>>(
        y2, Wout2, (const float*)nullptr, part1, (float*)nullptr, 1 << 30,
        1024, 1024, 2048, 32, 1024, (size_t)2048 * 1024);
    combine2<<<2048, blk, 0, stream>>>(part1, part2, b_out, out);
}

// Round 10
// 327.618 us; speedup vs baseline: 1.4125x; 1.0074x over previous
//
#include <hip/hip_runtime.h>
#include <math.h>

// Mamba block. GEMMs: f16 split-2 ([hi|lo] planes), templated MFMA GEMM.
// GEMM1: 256x128 tile, 8 waves, 3-buffer LDS ring (one barrier/iter, early
// stage-issue, counted vmcnt). GEMM2/3: 128x128, 4 waves, 2-buffer.
// GEMM3 split-K=4. Merged converter launches. Chunked parallel scan.

typedef _Float16 half8 __attribute__((ext_vector_type(8)));
typedef float floatx4 __attribute__((ext_vector_type(4)));

#define NSTATE 16
#define NCHUNK 32
#define LCHUNK 32

__device__ __forceinline__ void gload_lds16(const _Float16* g, _Float16* l) {
    __builtin_amdgcn_global_load_lds(
        (const __attribute__((address_space(1))) unsigned int*)g,
        (__attribute__((address_space(3))) unsigned int*)l, 16, 0, 0);
}

// ---------- converter body: fp32 [R][K] -> f16 [Rpad][2K] = [hi | lo] -------
__device__ __forceinline__ void convert_body(
    const float* __restrict__ src, _Float16* __restrict__ dst,
    int R, int K, int blk, int tid)
{
    int idx = blk * 256 + tid;
    int nck = K >> 3;
    int r = idx / nck;
    int g = idx - r * nck;
    half8 h, l;
    if (r < R) {
        const float* sp = src + (size_t)r * K + g * 8;
        #pragma unroll
        for (int e = 0; e < 8; ++e) {
            float x = sp[e];
            _Float16 hv = (_Float16)x;
            h[e] = hv;
            l[e] = (_Float16)(x - (float)hv);
        }
    } else {
        #pragma unroll
        for (int e = 0; e < 8; ++e) { h[e] = (_Float16)0.f; l[e] = (_Float16)0.f; }
    }
    _Float16* dp = dst + (size_t)r * 2 * K + g * 8;
    *(half8*)dp = h;
    *(half8*)(dp + K) = l;
}

// merged upfront converters: x (1024 blk) | W_in (2048 blk) | W_x (2176 blk)
__global__ __launch_bounds__(256) void convAll(
    const float* __restrict__ x, const float* __restrict__ W_in,
    const float* __restrict__ W_x, _Float16* __restrict__ xh2,
    _Float16* __restrict__ Win2, _Float16* __restrict__ Wx2)
{
    int b = blockIdx.x;
    if (b < 1024)       convert_body(x,    xh2,  2048, 1024, b,        threadIdx.x);
    else if (b < 3072)  convert_body(W_in, Win2, 4096, 1024, b - 1024, threadIdx.x);
    else                convert_body(W_x,  Wx2,  2080, 2048, b - 3072, threadIdx.x);
}

// ---------- MFMA GEMM: C[M,N](fp32) = A2[M,2K](f16 hi|lo) @ W2[Npad,2K]^T ----
// RING==2: vmcnt(N); bar; read+MFMA; bar; stage(k+2)->buf[k&1].
// RING==3: vmcnt(N); bar; stage(k+2)->buf[(k+2)%3]; read buf[k%3]+MFMA.
template<int BM, int BN, int WGN, int WAVES, int NLOADS, int RING>
__global__ __launch_bounds__(WAVES * 64, 2) void hgemmT(
    const _Float16* __restrict__ A2, const _Float16* __restrict__ W2,
    const float* __restrict__ bias, float* __restrict__ C, float* __restrict__ C2,
    int colSplit, int ldc, int Nvalid, int K, int kSteps,
    int kzStride, size_t zStrideC)
{
    constexpr int BUFH = (BM + BN) * 64;   // halfs per buffer
    __shared__ _Float16 lds[RING * BUFH];

    // XCD-chunked bijective block swizzle (nwg % 8 == 0)
    const int nbx = gridDim.x;
    const int h = blockIdx.y * nbx + blockIdx.x;
    const int nwg = nbx * gridDim.y;
    const int cpx = nwg >> 3;
    const int e = (h & 7) * cpx + (h >> 3);
    const int by = e / nbx, bx = e - by * nbx;

    const int tid = threadIdx.x;
    const int lane = tid & 63;
    const int wid = tid >> 6;
    const int wm = wid / WGN, wn = wid % WGN;
    const int m0 = by * BM, n0 = bx * BN;
    const int kg = lane >> 4, fr = lane & 15;
    const size_t K2 = (size_t)2 * K;
    const int kBegin = blockIdx.z * kzStride;

    // staging plan: thread covers chunks c = (wid*NLOADS + j)*64 + lane
    // planes (16B chunks): Ah [0,4BM) | Al [4BM,8BM) | Wh [..,+4BN) | Wl
    const _Float16* src[NLOADS];
    int dstH[NLOADS];
    #pragma unroll
    for (int j = 0; j < NLOADS; ++j) {
        int c = (wid * NLOADS + j) * 64 + lane;
        int isa, limb, pr;
        if (c < 4 * BM)                    { isa = 1; limb = 0; pr = c; }
        else if (c < 8 * BM)               { isa = 1; limb = 1; pr = c - 4 * BM; }
        else if (c < 8 * BM + 4 * BN)      { isa = 0; limb = 0; pr = c - 8 * BM; }
        else                               { isa = 0; limb = 1; pr = c - 8 * BM - 4 * BN; }
        int row = pr >> 2, cc = pr & 3;
        int sw = (row >> 1) & 3;                       // source XOR swizzle
        const _Float16* base = isa ? A2 + (size_t)(m0 + row) * K2
                                   : W2 + (size_t)(n0 + row) * K2;
        src[j] = base + (size_t)limb * K + kBegin + ((cc ^ sw) << 3);
        dstH[j] = (wid * NLOADS + j) * 512;            // wave-uniform base
    }

    floatx4 acc[4][4];
    #pragma unroll
    for (int mi = 0; mi < 4; ++mi)
        #pragma unroll
        for (int ni = 0; ni < 4; ++ni)
            acc[mi][ni] = (floatx4){0.f, 0.f, 0.f, 0.f};

    const int ksw = (kg ^ ((fr >> 1) & 3)) << 3;       // read-side swizzle

    // prologue: tile0 -> buf0, tile1 -> buf1
    #pragma unroll
    for (int j = 0; j < NLOADS; ++j)
        gload_lds16(src[j], lds + dstH[j]);
    #pragma unroll
    for (int j = 0; j < NLOADS; ++j)
        gload_lds16(src[j] + 32, lds + BUFH + dstH[j]);

    for (int ks = 0; ks < kSteps; ++ks) {
        if constexpr (NLOADS == 6)
            asm volatile("s_waitcnt vmcnt(6)" ::: "memory");
        else
            asm volatile("s_waitcnt vmcnt(8)" ::: "memory");
        __builtin_amdgcn_s_barrier();
        __builtin_amdgcn_sched_barrier(0);

        int kt = ks + 2; if (kt > kSteps - 1) kt = kSteps - 1;  // uniform vmcnt tail
        if constexpr (RING == 3) {
            // stage early into the free ring slot (not read, not in flight)
            #pragma unroll
            for (int j = 0; j < NLOADS; ++j)
                gload_lds16(src[j] + (size_t)kt * 32,
                            lds + ((ks + 2) % 3) * BUFH + dstH[j]);
            __builtin_amdgcn_sched_barrier(0);
        }

        const _Float16* buf = lds + (RING == 3 ? (ks % 3) : (ks & 1)) * BUFH;
        half8 ah[4], al[4], wh[4], wl[4];
        #pragma unroll
        for (int ni = 0; ni < 4; ++ni) {
            int off = 2 * BM * 32 + (wn * 64 + ni * 16 + fr) * 32 + ksw;
            wh[ni] = *(const half8*)(buf + off);
            wl[ni] = *(const half8*)(buf + BN * 32 + off);
        }
        #pragma unroll
        for (int mi = 0; mi < 4; ++mi) {
            int off = (wm * 64 + mi * 16 + fr) * 32 + ksw;
            ah[mi] = *(const half8*)(buf + off);
            al[mi] = *(const half8*)(buf + BM * 32 + off);
        }
        #pragma unroll
        for (int mi = 0; mi < 4; ++mi)
            #pragma unroll
            for (int ni = 0; ni < 4; ++ni) {
                floatx4 a = acc[mi][ni];
                a = __builtin_amdgcn_mfma_f32_16x16x32_f16(ah[mi], wh[ni], a, 0, 0, 0);
                a = __builtin_amdgcn_mfma_f32_16x16x32_f16(ah[mi], wl[ni], a, 0, 0, 0);
                a = __builtin_amdgcn_mfma_f32_16x16x32_f16(al[mi], wh[ni], a, 0, 0, 0);
                acc[mi][ni] = a;
            }

        if constexpr (RING == 2) {
            __builtin_amdgcn_s_barrier();        // all waves done reading buf[ks&1]
            __builtin_amdgcn_sched_barrier(0);
            #pragma unroll
            for (int j = 0; j < NLOADS; ++j)
                gload_lds16(src[j] + (size_t)kt * 32, lds + (ks & 1) * BUFH + dstH[j]);
        }
    }

    asm volatile("s_waitcnt vmcnt(0)" ::: "memory");  // drain DMA before exit

    // epilogue: col = fr, row-in-frag = kg*4 + r
    float* Cz = C + blockIdx.z * zStrideC;
    #pragma unroll
    for (int ni = 0; ni < 4; ++ni) {
        int nn = n0 + wn * 64 + ni * 16 + fr;
        if (nn >= Nvalid) continue;
        float bv = bias ? bias[nn] : 0.f;
        float* Cp = Cz;
        int col = nn;
        if (C2 && nn >= colSplit) { Cp = C2; col = nn - colSplit; }
        #pragma unroll
        for (int mi = 0; mi < 4; ++mi) {
            int mm = m0 + wm * 64 + mi * 16 + kg * 4;
            float* ptr = Cp + (size_t)mm * ldc + col;
            #pragma unroll
            for (int r = 0; r < 4; ++r)
                ptr[(size_t)r * ldc] = acc[mi][ni][r] + bv;
        }
    }
}

// ---------- conv + silu (2048 blk) merged with W_out converter (1024 blk) ----
__global__ __launch_bounds__(256) void conv_silu_wout(
    const float* __restrict__ xc, const float* __restrict__ conv_w,
    const float* __restrict__ conv_b, _Float16* __restrict__ xcs2,
    const float* __restrict__ W_out, _Float16* __restrict__ Wout2)
{
    if (blockIdx.x >= 2048) {
        convert_body(W_out, Wout2, 1024, 2048, blockIdx.x - 2048, threadIdx.x);
        return;
    }
    const int D = 2048, L = 1024;
    int idx = blockIdx.x * 256 + threadIdx.x;
    int g = idx & 255;
    int l = (idx >> 8) & (L - 1);
    int b = idx >> 18;
    int d0 = g * 8;
    int row = b * L + l;

    float a[8];
    #pragma unroll
    for (int j = 0; j < 8; ++j) a[j] = conv_b[d0 + j];
    #pragma unroll
    for (int t = 0; t < 4; ++t) {
        int lt = l - 3 + t;
        if (lt >= 0) {
            const float* rp = xc + (size_t)(b * L + lt) * D + d0;
            #pragma unroll
            for (int j = 0; j < 8; ++j)
                a[j] = fmaf(rp[j], conv_w[(d0 + j) * 4 + t], a[j]);
        }
    }
    half8 h, lo;
    #pragma unroll
    for (int j = 0; j < 8; ++j) {
        float v = a[j];
        float s = v / (1.f + expf(-v));
        _Float16 hv = (_Float16)s;
        h[j] = hv;
        lo[j] = (_Float16)(s - (float)hv);
    }
    _Float16* dp = xcs2 + (size_t)row * 4096 + d0;
    *(half8*)dp = h;
    *(half8*)(dp + 2048) = lo;
}

__device__ __forceinline__ float softplusf(float x) {
    return (x > 20.f) ? x : log1pf(expf(x));
}

// ---------- chunked scan ----------
__global__ __launch_bounds__(256) void scan_pass1(
    const float* __restrict__ dbu, const float* __restrict__ W_dt,
    const float* __restrict__ b_dt, const float* __restrict__ A_log,
    float* __restrict__ Sout, float* __restrict__ Pout)
{
    const int D = 2048, L = 1024, NDBU = 2080;
    const int g = blockIdx.x & 7;
    const int c = (blockIdx.x >> 3) & (NCHUNK - 1);
    const int b = blockIdx.x >> 8;
    const int d = g * 256 + threadIdx.x;

    float wdt[NSTATE], Aneg[NSTATE], s[NSTATE], P[NSTATE];
    #pragma unroll
    for (int n = 0; n < NSTATE; ++n) {
        wdt[n] = W_dt[d * NSTATE + n];
        Aneg[n] = -expf(A_log[d * NSTATE + n]);
        s[n] = 0.f; P[n] = 1.f;
    }
    const float bdt = b_dt[d];

    __shared__ float sbuf[LCHUNK][33];
    {
        int r = threadIdx.x >> 3;
        int c4 = (threadIdx.x & 7) * 4;
        float4 v = *(const float4*)(dbu + ((size_t)b * L + c * LCHUNK + r) * NDBU + c4);
        sbuf[r][c4 + 0] = v.x; sbuf[r][c4 + 1] = v.y;
        sbuf[r][c4 + 2] = v.z; sbuf[r][c4 + 3] = v.w;
    }
    __syncthreads();

    for (int li = 0; li < LCHUNK; ++li) {
        const int l = c * LCHUNK + li;
        const float u = dbu[((size_t)b * L + l) * NDBU + 32 + d];
        float accd = bdt;
        #pragma unroll
        for (int n = 0; n < NSTATE; ++n) accd = fmaf(sbuf[li][n], wdt[n], accd);
        const float delta = softplusf(accd);
        const float du = delta * u;
        #pragma unroll
        for (int n = 0; n < NSTATE; ++n) {
            float dA = expf(delta * Aneg[n]);
            s[n] = fmaf(dA, s[n], du * sbuf[li][16 + n]);
            P[n] *= dA;
        }
    }
    const size_t o = (((size_t)b * NCHUNK + c) * D + d) * NSTATE;
    #pragma unroll
    for (int n = 0; n < NSTATE; ++n) { Sout[o + n] = s[n]; Pout[o + n] = P[n]; }
}

__global__ __launch_bounds__(256) void scan_mid(
    const float* __restrict__ S, float* __restrict__ P)
{
    const int D = 2048;
    int idx = blockIdx.x * 256 + threadIdx.x;
    int n = idx & 15;
    int d = (idx >> 4) & (D - 1);
    int b = idx >> 15;
    float carry = 0.f;
    for (int c = 0; c < NCHUNK; ++c) {
        size_t o = (((size_t)b * NCHUNK + c) * D + d) * NSTATE + n;
        float Sv = S[o], Pv = P[o];
        P[o] = carry;
        carry = fmaf(Pv, carry, Sv);
    }
}

__global__ __launch_bounds__(256) void scan_pass2(
    const float* __restrict__ dbu, const float* __restrict__ z,
    const float* __restrict__ W_dt, const float* __restrict__ b_dt,
    const float* __restrict__ A_log, const float* __restrict__ Dp,
    const float* __restrict__ CarryIn, _Float16* __restrict__ y2)
{
    const int D = 2048, L = 1024, NDBU = 2080;
    const int g = blockIdx.x & 7;
    const int c = (blockIdx.x >> 3) & (NCHUNK - 1);
    const int b = blockIdx.x >> 8;
    const int d = g * 256 + threadIdx.x;

    float wdt[NSTATE], Aneg[NSTATE], s[NSTATE];
    const size_t o = (((size_t)b * NCHUNK + c) * D + d) * NSTATE;
    #pragma unroll
    for (int n = 0; n < NSTATE; ++n) {
        wdt[n] = W_dt[d * NSTATE + n];
        Aneg[n] = -expf(A_log[d * NSTATE + n]);
        s[n] = CarryIn[o + n];
    }
    const float bdt = b_dt[d];
    const float dp = Dp[d];

    __shared__ float sbuf[LCHUNK][33];
    {
        int r = threadIdx.x >> 3;
        int c4 = (threadIdx.x & 7) * 4;
        float4 v = *(const float4*)(dbu + ((size_t)b * L + c * LCHUNK + r) * NDBU + c4);
        sbuf[r][c4 + 0] = v.x; sbuf[r][c4 + 1] = v.y;
        sbuf[r][c4 + 2] = v.z; sbuf[r][c4 + 3] = v.w;
    }
    __syncthreads();

    for (int li = 0; li < LCHUNK; ++li) {
        const int l = c * LCHUNK + li;
        const int row = b * L + l;
        const float u = dbu[(size_t)row * NDBU + 32 + d];
        float accd = bdt;
        #pragma unroll
        for (int n = 0; n < NSTATE; ++n) accd = fmaf(sbuf[li][n], wdt[n], accd);
        const float delta = softplusf(accd);
        const float du = delta * u;
        float sum = 0.f;
        #pragma unroll
        for (int n = 0; n < NSTATE; ++n) {
            float dA = expf(delta * Aneg[n]);
            s[n] = fmaf(dA, s[n], du * sbuf[li][16 + n]);
            sum += s[n];
        }
        const float zz = z[(size_t)row * D + d];
        const float yv = (sum + u) * dp * (zz / (1.f + expf(-zz)));
        _Float16 hv = (_Float16)yv;
        y2[(size_t)row * 4096 + d] = hv;
        y2[(size_t)row * 4096 + 2048 + d] = (_Float16)(yv - (float)hv);
    }
}

// ---------- combine 4 split-K partials + bias ----------
__global__ __launch_bounds__(256) void combine4(
    const float* __restrict__ parts, const float* __restrict__ bias,
    float* __restrict__ out)
{
    const size_t PS = (size_t)2048 * 1024;
    int i = (blockIdx.x * 256 + threadIdx.x) * 4;
    int n = i & 1023;
    float4 a = *(const float4*)(parts + i);
    float4 b = *(const float4*)(parts + PS + i);
    float4 cc = *(const float4*)(parts + 2 * PS + i);
    float4 dd = *(const float4*)(parts + 3 * PS + i);
    float4 bb = *(const float4*)(bias + n);
    float4 r;
    r.x = a.x + b.x + cc.x + dd.x + bb.x;
    r.y = a.y + b.y + cc.y + dd.y + bb.y;
    r.z = a.z + b.z + cc.z + dd.z + bb.z;
    r.w = a.w + b.w + cc.w + dd.w + bb.w;
    *(float4*)(out + i) = r;
}

extern "C" void kernel_launch(void* const* d_in, const int* in_sizes, int n_in,
                              void* d_out, int out_size, void* d_ws, size_t ws_size,
                              hipStream_t stream) {
    const float* x      = (const float*)d_in[0];
    const float* W_in   = (const float*)d_in[1];
    const float* b_in   = (const float*)d_in[2];
    const float* conv_w = (const float*)d_in[3];
    const float* conv_b = (const float*)d_in[4];
    const float* W_x    = (const float*)d_in[5];
    const float* b_x    = (const float*)d_in[6];
    const float* W_dt   = (const float*)d_in[7];
    const float* b_dt   = (const float*)d_in[8];
    const float* A_log  = (const float*)d_in[9];
    const float* Dp     = (const float*)d_in[10];
    const float* W_out  = (const float*)d_in[11];
    const float* b_out  = (const float*)d_in[12];
    float* out = (float*)d_out;

    // ws (bytes), high-water ~77.9MB (R1 proved >=84MB available):
    //  z/parts @ 0        : fp32 z 16.8MB; later 4x8.4MB GEMM3 partials (33.5MB,
    //                       overlays z+dbu, both dead after pass2)
    //  xc/dbu  @ 16777216 : fp32 [2048][2080] (17.04MB)
    //  big     @ 33816576 : f16 16.8MB {Win2 -> xcs2 -> y2}
    //  aux     @ 50593792 : f16 Wx2 [2176][4096] (17.8MB); later S(8.4)+P(8.4)
    //  whi     @ 69468160 : f16 8.4MB {xh2 -> Wout2}
    char* ws = (char*)d_ws;
    float*    z     = (float*)(ws);
    float*    xc    = (float*)(ws + 16777216);
    float*    dbu   = xc;
    _Float16* big   = (_Float16*)(ws + 33816576);
    _Float16* aux   = (_Float16*)(ws + 50593792);
    _Float16* whi   = (_Float16*)(ws + 69468160);

    _Float16* Win2  = big;                 // [4096][2048]
    _Float16* xh2   = whi;                 // [2048][2048]
    _Float16* xcs2  = big;                 // [2048][4096]
    _Float16* Wx2   = aux;                 // [2176][4096]
    float*    Sb    = (float*)aux;         // after GEMM2 (Wx2 dead)
    float*    Pb    = Sb + (size_t)2 * NCHUNK * 2048 * NSTATE;
    _Float16* y2    = big;                 // [2048][4096]
    _Float16* Wout2 = whi;                 // [1024][4096] (xh2 dead after GEMM1)
    float*    parts = (float*)ws;          // 4 x [2048][1024] (z+dbu dead)

    dim3 blk(256);

    // 1. all input converters in one launch: x | W_in | W_x
    convAll<<<1024 + 2048 + 2176, blk, 0, stream>>>(x, W_in, W_x, xh2, Win2, Wx2);

    // 2. GEMM1: xz = x @ W_in.T + b_in -> xc (cols<2048) and z (cols>=2048)
    //    BM=256, BN=128, 8 waves, 3-ring LDS (144KB), grid 32x8 = 256 blocks
    hgemmT<256, 128, 2, 8, 6, 3><<<dim3(32, 8, 1), dim3(512), 0, stream>>>(
        xh2, Win2, b_in, xc, z, 2048, 2048, 4096, 1024, 32, 0, 0);

    // 3. conv + silu -> xcs2 (f16 hi|lo), merged with W_out converter
    conv_silu_wout<<<2048 + 1024, blk, 0, stream>>>(
        xc, conv_w, conv_b, xcs2, W_out, Wout2);

    // 4. GEMM2: dbu = xcs @ W_x.T + b_x  (N=2176 pad; grid 17x16 = 272, 2-buf)
    hgemmT<128, 128, 2, 4, 8, 2><<<dim3(17, 16, 1), blk, 0, stream>>>(
        xcs2, Wx2, b_x, dbu, (float*)nullptr, 1 << 30, 2080, 2080, 2048, 64, 0, 0);

    // 5. chunked scan -> y2 (f16 hi|lo)
    scan_pass1<<<2 * NCHUNK * 8, blk, 0, stream>>>(dbu, W_dt, b_dt, A_log, Sb, Pb);
    scan_mid<<<(2 * 2048 * NSTATE) / 256, blk, 0, stream>>>(Sb, Pb);
    scan_pass2<<<2 * NCHUNK * 8, blk, 0, stream>>>(dbu, z, W_dt, b_dt, A_log, Dp, Pb, y2);

    // 6. GEMM3 (split-K=4): out = y @ W_out.T + b_out (grid 8x16x4 = 512 blocks)
    hgemmT<128, 128, 2, 4, 8, 2><<<dim3(8, 16, 4), blk, 0, stream>>>(
        y2, Wout2, (const float*)nullptr, parts, (float*)nullptr, 1 << 30,
        1024, 1024, 2048, 16, 512, (size_t)2048 * 1024);
    combine4<<<2048, blk, 0, stream>>>(parts, b_out, out);
}

// Round 11
// 322.970 us; speedup vs baseline: 1.4329x; 1.0144x over previous
//
#include <hip/hip_runtime.h>
#include <math.h>

// Mamba block. GEMMs: f16 split-2 ([hi|lo] planes) on a 3-phase plane-staggered
// pipeline (T3+T4): 256x128 tile, 8 waves (4Mx2N), 2x48KB LDS, counted vmcnt(4)
// (never 0 in-loop), per-phase {ds_read || stage-issue || MFMA} interleave,
// setprio around MFMA, source+read XOR swizzle, XCD block swizzle.
// Chunked parallel scan, fused conv/silu.

typedef _Float16 half8 __attribute__((ext_vector_type(8)));
typedef float floatx4 __attribute__((ext_vector_type(4)));

#define NSTATE 16
#define NCHUNK 32
#define LCHUNK 32

__device__ __forceinline__ void gload_lds16(const _Float16* g, _Float16* l) {
    __builtin_amdgcn_global_load_lds(
        (const __attribute__((address_space(1))) unsigned int*)g,
        (__attribute__((address_space(3))) unsigned int*)l, 16, 0, 0);
}

#define MFMA16x16x32(a, b, c) __builtin_amdgcn_mfma_f32_16x16x32_f16(a, b, c, 0, 0, 0)

// ---------- converter body: fp32 [R][K] -> f16 [Rpad][2K] = [hi | lo] -------
__device__ __forceinline__ void convert_body(
    const float* __restrict__ src, _Float16* __restrict__ dst,
    int R, int K, int blk, int tid)
{
    int idx = blk * 256 + tid;
    int nck = K >> 3;
    int r = idx / nck;
    int g = idx - r * nck;
    half8 h, l;
    if (r < R) {
        const float* sp = src + (size_t)r * K + g * 8;
        #pragma unroll
        for (int e = 0; e < 8; ++e) {
            float x = sp[e];
            _Float16 hv = (_Float16)x;
            h[e] = hv;
            l[e] = (_Float16)(x - (float)hv);
        }
    } else {
        #pragma unroll
        for (int e = 0; e < 8; ++e) { h[e] = (_Float16)0.f; l[e] = (_Float16)0.f; }
    }
    _Float16* dp = dst + (size_t)r * 2 * K + g * 8;
    *(half8*)dp = h;
    *(half8*)(dp + K) = l;
}

// merged upfront converters: x (1024 blk) | W_in (2048 blk) | W_x (2176 blk)
__global__ __launch_bounds__(256) void convAll(
    const float* __restrict__ x, const float* __restrict__ W_in,
    const float* __restrict__ W_x, _Float16* __restrict__ xh2,
    _Float16* __restrict__ Win2, _Float16* __restrict__ Wx2)
{
    int b = blockIdx.x;
    if (b < 1024)       convert_body(x,    xh2,  2048, 1024, b,        threadIdx.x);
    else if (b < 3072)  convert_body(W_in, Win2, 4096, 1024, b - 1024, threadIdx.x);
    else                convert_body(W_x,  Wx2,  2080, 2048, b - 3072, threadIdx.x);
}

// ---------- hgemm8: C[M,N](fp32) = A2[M,2K](f16 hi|lo) @ W2[Npad,2K]^T ------
// Tile 256(M) x 128(N), 8 waves 4Mx2N (wave 64x64), BK = 32 fp32 pairs.
// LDS buffer (halfs): Ah[256][32]@0 | Al@8192 | Wh[128][32]@16384 | Wl@20480
// = 48KB; 2 buffers (96KB). 3 phases per K-tile; plane-staggered staging:
//   P0: read wh,wl,ah01; stage Al(t+1)->other buf; 16 MFMA
//   P1: read al01,ah23;  stage Wh,Wl(t+2)->this buf (consumed in P0); 24 MFMA
//   P2: read al23;       stage Ah(t+2)->this buf (consumed by P1);     8 MFMA
// vmcnt(4) at P0-top (= the 4 loads newer than this tile's Al), then barrier.
__global__ __launch_bounds__(512, 2) void hgemm8(
    const _Float16* __restrict__ A2, const _Float16* __restrict__ W2,
    const float* __restrict__ bias, float* __restrict__ C, float* __restrict__ C2,
    int colSplit, int ldc, int Nvalid, int K, int kSteps,
    int kzStride, size_t zStrideC)
{
    __shared__ _Float16 lds[2 * 24576];   // 96 KB

    // XCD-chunked bijective block swizzle (nwg % 8 == 0)
    const int nbx = gridDim.x;
    const int h = blockIdx.y * nbx + blockIdx.x;
    const int nwg = nbx * gridDim.y;
    const int cpx = nwg >> 3;
    const int e = (h & 7) * cpx + (h >> 3);
    const int by = e / nbx, bx = e - by * nbx;

    const int tid = threadIdx.x;
    const int lane = tid & 63;
    const int wid = tid >> 6;
    const int wm = wid >> 1, wn = wid & 1;      // wave 64x64 at (wm*64, wn*64)
    const int m0 = by * 256, n0 = bx * 128;
    const int kg = lane >> 4, fr = lane & 15;
    const size_t K2 = (size_t)2 * K;
    const int kBegin = blockIdx.z * kzStride;

    // staging pointers. A-planes: 1024 chunks (2 loads/thread); W-planes: 512
    // (1 load/thread). Source XOR-swizzled: LDS[r][c] = G[r][c ^ ((r>>1)&3)].
    const int srow = lane >> 2;      // 0..15
    const int scc  = lane & 3;
    const _Float16* psrcA0; const _Float16* psrcA1;
    const _Float16* psrcW0; const _Float16* psrcW1;
    {
        int rowA = wid * 32 + srow;                  // i=1 adds 16: swizzle invariant
        int swA = (rowA >> 1) & 3;
        const _Float16* bA = A2 + (size_t)(m0 + rowA) * K2 + kBegin + ((scc ^ swA) << 3);
        psrcA0 = bA; psrcA1 = bA + K;
        int rowW = wid * 16 + srow;
        int swW = (rowW >> 1) & 3;
        const _Float16* bW = W2 + (size_t)(n0 + rowW) * K2 + kBegin + ((scc ^ swW) << 3);
        psrcW0 = bW; psrcW1 = bW + K;
    }

#define SA0(kt, bb) { const _Float16* s_ = psrcA0 + (size_t)(kt) * 32;          \
        _Float16* d_ = (bb) + wid * 1024;                                       \
        gload_lds16(s_, d_); gload_lds16(s_ + (size_t)16 * K2, d_ + 512); }
#define SA1(kt, bb) { const _Float16* s_ = psrcA1 + (size_t)(kt) * 32;          \
        _Float16* d_ = (bb) + 8192 + wid * 1024;                                \
        gload_lds16(s_, d_); gload_lds16(s_ + (size_t)16 * K2, d_ + 512); }
#define SW0(kt, bb) gload_lds16(psrcW0 + (size_t)(kt) * 32, (bb) + 16384 + wid * 512);
#define SW1(kt, bb) gload_lds16(psrcW1 + (size_t)(kt) * 32, (bb) + 20480 + wid * 512);

    floatx4 acc[4][4];
    #pragma unroll
    for (int q = 0; q < 4; ++q)
        #pragma unroll
        for (int ni = 0; ni < 4; ++ni)
            acc[q][ni] = (floatx4){0.f, 0.f, 0.f, 0.f};

    const int ksw = (kg ^ ((fr >> 1) & 3)) << 3;     // read-side swizzle
    const int arow = (wm * 64 + fr) * 32 + ksw;      // + q*512 per m-frag
    const int wrow = (wn * 64 + fr) * 32 + ksw;      // + ni*512 per n-frag

    // prologue: Wh0,Wl0,Ah0,Al0 -> buf0 ; Wh1,Wl1,Ah1 -> buf1   (10 loads)
    SW0(0, lds) SW1(0, lds) SA0(0, lds) SA1(0, lds)
    SW0(1, lds + 24576) SW1(1, lds + 24576) SA0(1, lds + 24576)

    for (int t = 0; t < kSteps; ++t) {
        _Float16* bufR = lds + (t & 1) * 24576;
        _Float16* bufO = lds + ((t & 1) ^ 1) * 24576;
        const int t1 = (t + 1 < kSteps) ? t + 1 : kSteps - 1;
        const int t2 = (t + 2 < kSteps) ? t + 2 : kSteps - 1;

        // ---- P0 ----
        asm volatile("s_waitcnt vmcnt(4)" ::: "memory");   // tile t fully landed
        __builtin_amdgcn_s_barrier();
        __builtin_amdgcn_sched_barrier(0);
        half8 wh[4], wl[4];
        #pragma unroll
        for (int ni = 0; ni < 4; ++ni) {
            wh[ni] = *(const half8*)(bufR + 16384 + wrow + ni * 512);
            wl[ni] = *(const half8*)(bufR + 20480 + wrow + ni * 512);
        }
        half8 a0 = *(const half8*)(bufR + arow);
        half8 a1 = *(const half8*)(bufR + arow + 512);
        SA1(t1, bufO)                                   // Al(t+1); its slot consumed last iter
        asm volatile("s_waitcnt lgkmcnt(0)" ::: "memory");
        __builtin_amdgcn_sched_barrier(0);
        __builtin_amdgcn_s_setprio(1);
        #pragma unroll
        for (int ni = 0; ni < 4; ++ni) {
            acc[0][ni] = MFMA16x16x32(a0, wh[ni], acc[0][ni]);
            acc[0][ni] = MFMA16x16x32(a0, wl[ni], acc[0][ni]);
            acc[1][ni] = MFMA16x16x32(a1, wh[ni], acc[1][ni]);
            acc[1][ni] = MFMA16x16x32(a1, wl[ni], acc[1][ni]);
        }
        __builtin_amdgcn_s_setprio(0);
        __builtin_amdgcn_s_barrier();                   // Wh,Wl of t consumed
        __builtin_amdgcn_sched_barrier(0);

        // ---- P1 ----
        half8 b0 = *(const half8*)(bufR + 8192 + arow);
        half8 b1 = *(const half8*)(bufR + 8192 + arow + 512);
        half8 a2 = *(const half8*)(bufR + arow + 1024);
        half8 a3 = *(const half8*)(bufR + arow + 1536);
        SW0(t2, bufR) SW1(t2, bufR)                     // Wh,Wl(t+2) into freed slots
        asm volatile("s_waitcnt lgkmcnt(0)" ::: "memory");
        __builtin_amdgcn_sched_barrier(0);
        __builtin_amdgcn_s_setprio(1);
        #pragma unroll
        for (int ni = 0; ni < 4; ++ni) {
            acc[0][ni] = MFMA16x16x32(b0, wh[ni], acc[0][ni]);
            acc[1][ni] = MFMA16x16x32(b1, wh[ni], acc[1][ni]);
            acc[2][ni] = MFMA16x16x32(a2, wh[ni], acc[2][ni]);
            acc[2][ni] = MFMA16x16x32(a2, wl[ni], acc[2][ni]);
            acc[3][ni] = MFMA16x16x32(a3, wh[ni], acc[3][ni]);
            acc[3][ni] = MFMA16x16x32(a3, wl[ni], acc[3][ni]);
        }
        __builtin_amdgcn_s_setprio(0);
        __builtin_amdgcn_s_barrier();                   // Ah of t consumed (P0+P1)
        __builtin_amdgcn_sched_barrier(0);

        // ---- P2 ----
        half8 b2 = *(const half8*)(bufR + 8192 + arow + 1024);
        half8 b3 = *(const half8*)(bufR + 8192 + arow + 1536);
        SA0(t2, bufR)                                   // Ah(t+2) into freed slot
        asm volatile("s_waitcnt lgkmcnt(0)" ::: "memory");
        __builtin_amdgcn_sched_barrier(0);
        __builtin_amdgcn_s_setprio(1);
        #pragma unroll
        for (int ni = 0; ni < 4; ++ni) {
            acc[2][ni] = MFMA16x16x32(b2, wh[ni], acc[2][ni]);
            acc[3][ni] = MFMA16x16x32(b3, wh[ni], acc[3][ni]);
        }
        __builtin_amdgcn_s_setprio(0);
        // no trailing barrier: next iteration's vmcnt+barrier closes P2
        // (Al of t consumed here; its slot staged at next iter's P0)
    }

    asm volatile("s_waitcnt vmcnt(0)" ::: "memory");   // drain DMA before exit

    // epilogue: col = fr, row-in-frag = kg*4 + r
    float* Cz = C + blockIdx.z * zStrideC;
    #pragma unroll
    for (int ni = 0; ni < 4; ++ni) {
        int nn = n0 + wn * 64 + ni * 16 + fr;
        if (nn >= Nvalid) continue;
        float bv = bias ? bias[nn] : 0.f;
        float* Cp = Cz;
        int col = nn;
        if (C2 && nn >= colSplit) { Cp = C2; col = nn - colSplit; }
        #pragma unroll
        for (int q = 0; q < 4; ++q) {
            int mm = m0 + wm * 64 + q * 16 + kg * 4;
            float* ptr = Cp + (size_t)mm * ldc + col;
            #pragma unroll
            for (int r = 0; r < 4; ++r)
                ptr[(size_t)r * ldc] = acc[q][ni][r] + bv;
        }
    }
}

// ---------- conv + silu (2048 blk) merged with W_out converter (1024 blk) ----
__global__ __launch_bounds__(256) void conv_silu_wout(
    const float* __restrict__ xc, const float* __restrict__ conv_w,
    const float* __restrict__ conv_b, _Float16* __restrict__ xcs2,
    const float* __restrict__ W_out, _Float16* __restrict__ Wout2)
{
    if (blockIdx.x >= 2048) {
        convert_body(W_out, Wout2, 1024, 2048, blockIdx.x - 2048, threadIdx.x);
        return;
    }
    const int D = 2048, L = 1024;
    int idx = blockIdx.x * 256 + threadIdx.x;
    int g = idx & 255;
    int l = (idx >> 8) & (L - 1);
    int b = idx >> 18;
    int d0 = g * 8;
    int row = b * L + l;

    float a[8];
    #pragma unroll
    for (int j = 0; j < 8; ++j) a[j] = conv_b[d0 + j];
    #pragma unroll
    for (int t = 0; t < 4; ++t) {
        int lt = l - 3 + t;
        if (lt >= 0) {
            const float* rp = xc + (size_t)(b * L + lt) * D + d0;
            #pragma unroll
            for (int j = 0; j < 8; ++j)
                a[j] = fmaf(rp[j], conv_w[(d0 + j) * 4 + t], a[j]);
        }
    }
    half8 h, lo;
    #pragma unroll
    for (int j = 0; j < 8; ++j) {
        float v = a[j];
        float s = v / (1.f + expf(-v));
        _Float16 hv = (_Float16)s;
        h[j] = hv;
        lo[j] = (_Float16)(s - (float)hv);
    }
    _Float16* dp = xcs2 + (size_t)row * 4096 + d0;
    *(half8*)dp = h;
    *(half8*)(dp + 2048) = lo;
}

__device__ __forceinline__ float softplusf(float x) {
    return (x > 20.f) ? x : log1pf(expf(x));
}

// ---------- chunked scan ----------
__global__ __launch_bounds__(256) void scan_pass1(
    const float* __restrict__ dbu, const float* __restrict__ W_dt,
    const float* __restrict__ b_dt, const float* __restrict__ A_log,
    float* __restrict__ Sout, float* __restrict__ Pout)
{
    const int D = 2048, L = 1024, NDBU = 2080;
    const int g = blockIdx.x & 7;
    const int c = (blockIdx.x >> 3) & (NCHUNK - 1);
    const int b = blockIdx.x >> 8;
    const int d = g * 256 + threadIdx.x;

    float wdt[NSTATE], Aneg[NSTATE], s[NSTATE], P[NSTATE];
    #pragma unroll
    for (int n = 0; n < NSTATE; ++n) {
        wdt[n] = W_dt[d * NSTATE + n];
        Aneg[n] = -expf(A_log[d * NSTATE + n]);
        s[n] = 0.f; P[n] = 1.f;
    }
    const float bdt = b_dt[d];

    __shared__ float sbuf[LCHUNK][33];
    {
        int r = threadIdx.x >> 3;
        int c4 = (threadIdx.x & 7) * 4;
        float4 v = *(const float4*)(dbu + ((size_t)b * L + c * LCHUNK + r) * NDBU + c4);
        sbuf[r][c4 + 0] = v.x; sbuf[r][c4 + 1] = v.y;
        sbuf[r][c4 + 2] = v.z; sbuf[r][c4 + 3] = v.w;
    }
    __syncthreads();

    for (int li = 0; li < LCHUNK; ++li) {
        const int l = c * LCHUNK + li;
        const float u = dbu[((size_t)b * L + l) * NDBU + 32 + d];
        float accd = bdt;
        #pragma unroll
        for (int n = 0; n < NSTATE; ++n) accd = fmaf(sbuf[li][n], wdt[n], accd);
        const float delta = softplusf(accd);
        const float du = delta * u;
        #pragma unroll
        for (int n = 0; n < NSTATE; ++n) {
            float dA = expf(delta * Aneg[n]);
            s[n] = fmaf(dA, s[n], du * sbuf[li][16 + n]);
            P[n] *= dA;
        }
    }
    const size_t o = (((size_t)b * NCHUNK + c) * D + d) * NSTATE;
    #pragma unroll
    for (int n = 0; n < NSTATE; ++n) { Sout[o + n] = s[n]; Pout[o + n] = P[n]; }
}

__global__ __launch_bounds__(256) void scan_mid(
    const float* __restrict__ S, float* __restrict__ P)
{
    const int D = 2048;
    int idx = blockIdx.x * 256 + threadIdx.x;
    int n = idx & 15;
    int d = (idx >> 4) & (D - 1);
    int b = idx >> 15;
    float carry = 0.f;
    for (int c = 0; c < NCHUNK; ++c) {
        size_t o = (((size_t)b * NCHUNK + c) * D + d) * NSTATE + n;
        float Sv = S[o], Pv = P[o];
        P[o] = carry;
        carry = fmaf(Pv, carry, Sv);
    }
}

__global__ __launch_bounds__(256) void scan_pass2(
    const float* __restrict__ dbu, const float* __restrict__ z,
    const float* __restrict__ W_dt, const float* __restrict__ b_dt,
    const float* __restrict__ A_log, const float* __restrict__ Dp,
    const float* __restrict__ CarryIn, _Float16* __restrict__ y2)
{
    const int D = 2048, L = 1024, NDBU = 2080;
    const int g = blockIdx.x & 7;
    const int c = (blockIdx.x >> 3) & (NCHUNK - 1);
    const int b = blockIdx.x >> 8;
    const int d = g * 256 + threadIdx.x;

    float wdt[NSTATE], Aneg[NSTATE], s[NSTATE];
    const size_t o = (((size_t)b * NCHUNK + c) * D + d) * NSTATE;
    #pragma unroll
    for (int n = 0; n < NSTATE; ++n) {
        wdt[n] = W_dt[d * NSTATE + n];
        Aneg[n] = -expf(A_log[d * NSTATE + n]);
        s[n] = CarryIn[o + n];
    }
    const float bdt = b_dt[d];
    const float dp = Dp[d];

    __shared__ float sbuf[LCHUNK][33];
    {
        int r = threadIdx.x >> 3;
        int c4 = (threadIdx.x & 7) * 4;
        float4 v = *(const float4*)(dbu + ((size_t)b * L + c * LCHUNK + r) * NDBU + c4);
        sbuf[r][c4 + 0] = v.x; sbuf[r][c4 + 1] = v.y;
        sbuf[r][c4 + 2] = v.z; sbuf[r][c4 + 3] = v.w;
    }
    __syncthreads();

    for (int li = 0; li < LCHUNK; ++li) {
        const int l = c * LCHUNK + li;
        const int row = b * L + l;
        const float u = dbu[(size_t)row * NDBU + 32 + d];
        float accd = bdt;
        #pragma unroll
        for (int n = 0; n < NSTATE; ++n) accd = fmaf(sbuf[li][n], wdt[n], accd);
        const float delta = softplusf(accd);
        const float du = delta * u;
        float sum = 0.f;
        #pragma unroll
        for (int n = 0; n < NSTATE; ++n) {
            float dA = expf(delta * Aneg[n]);
            s[n] = fmaf(dA, s[n], du * sbuf[li][16 + n]);
            sum += s[n];
        }
        const float zz = z[(size_t)row * D + d];
        const float yv = (sum + u) * dp * (zz / (1.f + expf(-zz)));
        _Float16 hv = (_Float16)yv;
        y2[(size_t)row * 4096 + d] = hv;
        y2[(size_t)row * 4096 + 2048 + d] = (_Float16)(yv - (float)hv);
    }
}

// ---------- combine 4 split-K partials + bias ----------
__global__ __launch_bounds__(256) void combine4(
    const float* __restrict__ parts, const float* __restrict__ bias,
    float* __restrict__ out)
{
    const size_t PS = (size_t)2048 * 1024;
    int i = (blockIdx.x * 256 + threadIdx.x) * 4;
    int n = i & 1023;
    float4 a = *(const float4*)(parts + i);
    float4 b = *(const float4*)(parts + PS + i);
    float4 cc = *(const float4*)(parts + 2 * PS + i);
    float4 dd = *(const float4*)(parts + 3 * PS + i);
    float4 bb = *(const float4*)(bias + n);
    float4 r;
    r.x = a.x + b.x + cc.x + dd.x + bb.x;
    r.y = a.y + b.y + cc.y + dd.y + bb.y;
    r.z = a.z + b.z + cc.z + dd.z + bb.z;
    r.w = a.w + b.w + cc.w + dd.w + bb.w;
    *(float4*)(out + i) = r;
}

extern "C" void kernel_launch(void* const* d_in, const int* in_sizes, int n_in,
                              void* d_out, int out_size, void* d_ws, size_t ws_size,
                              hipStream_t stream) {
    const float* x      = (const float*)d_in[0];
    const float* W_in   = (const float*)d_in[1];
    const float* b_in   = (const float*)d_in[2];
    const float* conv_w = (const float*)d_in[3];
    const float* conv_b = (const float*)d_in[4];
    const float* W_x    = (const float*)d_in[5];
    const float* b_x    = (const float*)d_in[6];
    const float* W_dt   = (const float*)d_in[7];
    const float* b_dt   = (const float*)d_in[8];
    const float* A_log  = (const float*)d_in[9];
    const float* Dp     = (const float*)d_in[10];
    const float* W_out  = (const float*)d_in[11];
    const float* b_out  = (const float*)d_in[12];
    float* out = (float*)d_out;

    // ws (bytes):
    //  z/parts @ 0        : fp32 z 16.8MB; later 4x8.4MB GEMM3 partials
    //  xc/dbu  @ 16777216 : fp32 [2048][2080]
    //  big     @ 33816576 : f16 16.8MB {Win2 -> xcs2 -> y2}
    //  aux     @ 50593792 : f16 Wx2 [2176][4096]; later S(8.4)+P(8.4)
    //  whi     @ 69468160 : f16 8.4MB {xh2 -> Wout2}
    char* ws = (char*)d_ws;
    float*    z     = (float*)(ws);
    float*    xc    = (float*)(ws + 16777216);
    float*    dbu   = xc;
    _Float16* big   = (_Float16*)(ws + 33816576);
    _Float16* aux   = (_Float16*)(ws + 50593792);
    _Float16* whi   = (_Float16*)(ws + 69468160);

    _Float16* Win2  = big;                 // [4096][2048]
    _Float16* xh2   = whi;                 // [2048][2048]
    _Float16* xcs2  = big;                 // [2048][4096]
    _Float16* Wx2   = aux;                 // [2176][4096]
    float*    Sb    = (float*)aux;         // after GEMM2 (Wx2 dead)
    float*    Pb    = Sb + (size_t)2 * NCHUNK * 2048 * NSTATE;
    _Float16* y2    = big;                 // [2048][4096]
    _Float16* Wout2 = whi;                 // [1024][4096] (xh2 dead after GEMM1)
    float*    parts = (float*)ws;          // 4 x [2048][1024] (z+dbu dead)

    dim3 blk(256);

    // 1. all input converters in one launch: x | W_in | W_x
    convAll<<<1024 + 2048 + 2176, blk, 0, stream>>>(x, W_in, W_x, xh2, Win2, Wx2);

    // 2. GEMM1: xz = x @ W_in.T + b_in -> xc (cols<2048), z (cols>=2048)
    //    grid 32x8 = 256 blocks (full fill)
    hgemm8<<<dim3(32, 8, 1), dim3(512), 0, stream>>>(
        xh2, Win2, b_in, xc, z, 2048, 2048, 4096, 1024, 32, 0, 0);

    // 3. conv + silu -> xcs2 (f16 hi|lo), merged with W_out converter
    conv_silu_wout<<<2048 + 1024, blk, 0, stream>>>(
        xc, conv_w, conv_b, xcs2, W_out, Wout2);

    // 4. GEMM2: dbu = xcs @ W_x.T + b_x  (N pad 2176; grid 17x8 = 136 blocks)
    hgemm8<<<dim3(17, 8, 1), dim3(512), 0, stream>>>(
        xcs2, Wx2, b_x, dbu, (float*)nullptr, 1 << 30, 2080, 2080, 2048, 64, 0, 0);

    // 5. chunked scan -> y2 (f16 hi|lo)
    scan_pass1<<<2 * NCHUNK * 8, blk, 0, stream>>>(dbu, W_dt, b_dt, A_log, Sb, Pb);
    scan_mid<<<(2 * 2048 * NSTATE) / 256, blk, 0, stream>>>(Sb, Pb);
    scan_pass2<<<2 * NCHUNK * 8, blk, 0, stream>>>(dbu, z, W_dt, b_dt, A_log, Dp, Pb, y2);

    // 6. GEMM3 (split-K=4): out = y @ W_out.T + b_out (grid 8x8x4 = 256 blocks)
    hgemm8<<<dim3(8, 8, 4), dim3(512), 0, stream>>>(
        y2, Wout2, (const float*)nullptr, parts, (float*)nullptr, 1 << 30,
        1024, 1024, 2048, 16, 512, (size_t)2048 * 1024);
    combine4<<<2048, blk, 0, stream>>>(parts, b_out, out);
}

// Round 12
// 308.732 us; speedup vs baseline: 1.4990x; 1.0461x over previous
//
#include <hip/hip_runtime.h>
#include <math.h>

// Mamba block. GEMM operands pre-converted to f16 split-2 in a K-TILED layout:
//   X2t[kt][limb][Rtot][32 halfs], bank-swizzle (chunk ^= (row>>1)&3) baked in.
// => every global_load_lds stages 1KB of CONTIGUOUS global memory (the round-11
// profile showed all GEMMs bound at ~5.3 TB/s staging delivery with scattered
// 16-row x 64B loads). GEMM loop = round-9 proven 2-phase counted-vmcnt.
// Chunked parallel scan, fused conv/silu.

typedef _Float16 half8 __attribute__((ext_vector_type(8)));
typedef float floatx4 __attribute__((ext_vector_type(4)));

#define NSTATE 16
#define NCHUNK 32
#define LCHUNK 32

__device__ __forceinline__ void gload_lds16(const _Float16* g, _Float16* l) {
    __builtin_amdgcn_global_load_lds(
        (const __attribute__((address_space(1))) unsigned int*)g,
        (__attribute__((address_space(3))) unsigned int*)l, 16, 0, 0);
}

// ---------- converter body: fp32 [R][K] -> tiled f16 hi|lo slabs ----------
// dst layout: [kt][limb][Rtot][32 halfs], chunk cc stored at cc ^ ((r>>1)&3).
__device__ __forceinline__ void convert_body(
    const float* __restrict__ src, _Float16* __restrict__ dst,
    int R, int Rtot, int K, int blk, int tid)
{
    int idx = blk * 256 + tid;          // over Rtot * (K/8) chunks of 8 fp32
    int nck = K >> 3;
    int r = idx / nck;
    int g = idx - r * nck;
    half8 h, l;
    if (r < R) {
        const float* sp = src + (size_t)r * K + g * 8;
        #pragma unroll
        for (int e = 0; e < 8; ++e) {
            float x = sp[e];
            _Float16 hv = (_Float16)x;
            h[e] = hv;
            l[e] = (_Float16)(x - (float)hv);
        }
    } else {
        #pragma unroll
        for (int e = 0; e < 8; ++e) { h[e] = (_Float16)0.f; l[e] = (_Float16)0.f; }
    }
    int kt = g >> 2;                    // K-tile (32 fp32)
    int cc = g & 3;                     // 16B chunk within slab row
    int sw = (r >> 1) & 3;
    size_t o = ((size_t)(kt * 2) * Rtot + r) * 32 + ((cc ^ sw) << 3);
    *(half8*)(dst + o) = h;                               // hi slab (limb 0)
    *(half8*)(dst + o + (size_t)Rtot * 32) = l;           // lo slab (limb 1)
}

// merged upfront converters: x (1024 blk) | W_in (2048 blk) | W_x (2176 blk)
__global__ __launch_bounds__(256) void convAll(
    const float* __restrict__ x, const float* __restrict__ W_in,
    const float* __restrict__ W_x, _Float16* __restrict__ xh2,
    _Float16* __restrict__ Win2, _Float16* __restrict__ Wx2)
{
    int b = blockIdx.x;
    if (b < 1024)       convert_body(x,    xh2,  2048, 2048, 1024, b,        threadIdx.x);
    else if (b < 3072)  convert_body(W_in, Win2, 4096, 4096, 1024, b - 1024, threadIdx.x);
    else                convert_body(W_x,  Wx2,  2080, 2176, 2048, b - 3072, threadIdx.x);
}

// ---------- MFMA GEMM: C[M,N](fp32) = A2t @ W2t^T (tiled operands) ----------
// Block BM x BN, WAVES waves (2 in N), wave tile 64x64, BK = 32 fp32 pairs.
// LDS buffer: Ah[BM][32] | Al | Wh[BN][32] | Wl, 2 buffers; staging = NLOADS
// contiguous-1KB global_load_lds per wave per K-tile; counted vmcnt.
template<int BM, int BN, int WGN, int WAVES, int NLOADS>
__global__ __launch_bounds__(WAVES * 64, 2) void hgemmT(
    const _Float16* __restrict__ A2, const _Float16* __restrict__ W2,
    const float* __restrict__ bias, float* __restrict__ C, float* __restrict__ C2,
    int colSplit, int ldc, int Nvalid, int RA, int RW, int kSteps,
    int ktzStride, size_t zStrideC)
{
    constexpr int BUFH = (BM + BN) * 64;   // halfs per buffer
    __shared__ _Float16 lds[2 * BUFH];

    // XCD-chunked bijective block swizzle (nwg % 8 == 0)
    const int nbx = gridDim.x;
    const int h = blockIdx.y * nbx + blockIdx.x;
    const int nwg = nbx * gridDim.y;
    const int cpx = nwg >> 3;
    const int e = (h & 7) * cpx + (h >> 3);
    const int by = e / nbx, bx = e - by * nbx;

    const int tid = threadIdx.x;
    const int lane = tid & 63;
    const int wid = tid >> 6;
    const int wm = wid / WGN, wn = wid % WGN;
    const int m0 = by * BM, n0 = bx * BN;
    const int kg = lane >> 4, fr = lane & 15;
    const int ktBegin = blockIdx.z * ktzStride;

    // staging plan: thread covers chunks c = (wid*NLOADS + j)*64 + lane.
    // chunk-planes: Ah [0,4BM) | Al [4BM,8BM) | Wh [..,+4BN) | Wl.
    // Tiled source: slab(kt,limb) base + r0*32 + pr*8 -> contiguous per load.
    const _Float16* src[NLOADS];
    size_t kstr[NLOADS];
    int dstH[NLOADS];
    #pragma unroll
    for (int j = 0; j < NLOADS; ++j) {
        int c = (wid * NLOADS + j) * 64 + lane;
        int isa, limb, pr;
        if (c < 4 * BM)                    { isa = 1; limb = 0; pr = c; }
        else if (c < 8 * BM)               { isa = 1; limb = 1; pr = c - 4 * BM; }
        else if (c < 8 * BM + 4 * BN)      { isa = 0; limb = 0; pr = c - 8 * BM; }
        else                               { isa = 0; limb = 1; pr = c - 8 * BM - 4 * BN; }
        int Rt = isa ? RA : RW;
        int r0 = isa ? m0 : n0;
        const _Float16* X = isa ? A2 : W2;
        src[j] = X + ((size_t)(ktBegin * 2 + limb) * Rt + r0) * 32 + pr * 8;
        kstr[j] = (size_t)2 * Rt * 32;           // halfs per K-tile step
        dstH[j] = (wid * NLOADS + j) * 512;      // wave-uniform linear dest
    }

    floatx4 acc[4][4];
    #pragma unroll
    for (int mi = 0; mi < 4; ++mi)
        #pragma unroll
        for (int ni = 0; ni < 4; ++ni)
            acc[mi][ni] = (floatx4){0.f, 0.f, 0.f, 0.f};

    const int ksw = (kg ^ ((fr >> 1) & 3)) << 3;       // read-side swizzle

    // prologue: tile0 -> buf0, tile1 -> buf1
    #pragma unroll
    for (int j = 0; j < NLOADS; ++j)
        gload_lds16(src[j], lds + dstH[j]);
    #pragma unroll
    for (int j = 0; j < NLOADS; ++j)
        gload_lds16(src[j] + kstr[j], lds + BUFH + dstH[j]);

    for (int ks = 0; ks < kSteps; ++ks) {
        if constexpr (NLOADS == 6)
            asm volatile("s_waitcnt vmcnt(6)" ::: "memory");
        else
            asm volatile("s_waitcnt vmcnt(8)" ::: "memory");
        __builtin_amdgcn_s_barrier();
        __builtin_amdgcn_sched_barrier(0);

        const _Float16* buf = lds + (ks & 1) * BUFH;
        half8 ah[4], al[4], wh[4], wl[4];
        #pragma unroll
        for (int ni = 0; ni < 4; ++ni) {
            int off = 2 * BM * 32 + (wn * 64 + ni * 16 + fr) * 32 + ksw;
            wh[ni] = *(const half8*)(buf + off);
            wl[ni] = *(const half8*)(buf + BN * 32 + off);
        }
        #pragma unroll
        for (int mi = 0; mi < 4; ++mi) {
            int off = (wm * 64 + mi * 16 + fr) * 32 + ksw;
            ah[mi] = *(const half8*)(buf + off);
            al[mi] = *(const half8*)(buf + BM * 32 + off);
        }
        __builtin_amdgcn_s_setprio(1);
        #pragma unroll
        for (int mi = 0; mi < 4; ++mi)
            #pragma unroll
            for (int ni = 0; ni < 4; ++ni) {
                floatx4 a = acc[mi][ni];
                a = __builtin_amdgcn_mfma_f32_16x16x32_f16(ah[mi], wh[ni], a, 0, 0, 0);
                a = __builtin_amdgcn_mfma_f32_16x16x32_f16(ah[mi], wl[ni], a, 0, 0, 0);
                a = __builtin_amdgcn_mfma_f32_16x16x32_f16(al[mi], wh[ni], a, 0, 0, 0);
                acc[mi][ni] = a;
            }
        __builtin_amdgcn_s_setprio(0);

        __builtin_amdgcn_s_barrier();            // all waves done reading buf[ks&1]
        __builtin_amdgcn_sched_barrier(0);
        int kt = ks + 2; if (kt > kSteps - 1) kt = kSteps - 1;  // uniform vmcnt tail
        #pragma unroll
        for (int j = 0; j < NLOADS; ++j)
            gload_lds16(src[j] + (size_t)kt * kstr[j], lds + (ks & 1) * BUFH + dstH[j]);
    }

    asm volatile("s_waitcnt vmcnt(0)" ::: "memory");  // drain DMA before exit

    // epilogue: col = fr, row-in-frag = kg*4 + r
    float* Cz = C + blockIdx.z * zStrideC;
    #pragma unroll
    for (int ni = 0; ni < 4; ++ni) {
        int nn = n0 + wn * 64 + ni * 16 + fr;
        if (nn >= Nvalid) continue;
        float bv = bias ? bias[nn] : 0.f;
        float* Cp = Cz;
        int col = nn;
        if (C2 && nn >= colSplit) { Cp = C2; col = nn - colSplit; }
        #pragma unroll
        for (int mi = 0; mi < 4; ++mi) {
            int mm = m0 + wm * 64 + mi * 16 + kg * 4;
            float* ptr = Cp + (size_t)mm * ldc + col;
            #pragma unroll
            for (int r = 0; r < 4; ++r)
                ptr[(size_t)r * ldc] = acc[mi][ni][r] + bv;
        }
    }
}

// ---------- conv + silu (2048 blk, tiled xcs2) + W_out converter (1024 blk) --
__global__ __launch_bounds__(256) void conv_silu_wout(
    const float* __restrict__ xc, const float* __restrict__ conv_w,
    const float* __restrict__ conv_b, _Float16* __restrict__ xcs2,
    const float* __restrict__ W_out, _Float16* __restrict__ Wout2)
{
    if (blockIdx.x >= 2048) {
        convert_body(W_out, Wout2, 1024, 1024, 2048, blockIdx.x - 2048, threadIdx.x);
        return;
    }
    const int D = 2048, L = 1024;
    int idx = blockIdx.x * 256 + threadIdx.x;
    int g = idx & 255;
    int l = (idx >> 8) & (L - 1);
    int b = idx >> 18;
    int d0 = g * 8;
    int row = b * L + l;

    float a[8];
    #pragma unroll
    for (int j = 0; j < 8; ++j) a[j] = conv_b[d0 + j];
    #pragma unroll
    for (int t = 0; t < 4; ++t) {
        int lt = l - 3 + t;
        if (lt >= 0) {
            const float* rp = xc + (size_t)(b * L + lt) * D + d0;
            #pragma unroll
            for (int j = 0; j < 8; ++j)
                a[j] = fmaf(rp[j], conv_w[(d0 + j) * 4 + t], a[j]);
        }
    }
    half8 h, lo;
    #pragma unroll
    for (int j = 0; j < 8; ++j) {
        float v = a[j];
        float s = v / (1.f + expf(-v));
        _Float16 hv = (_Float16)s;
        h[j] = hv;
        lo[j] = (_Float16)(s - (float)hv);
    }
    // tiled write: Rtot=2048, K=2048; kt=d0>>5, cc=(d0>>3)&3
    int kt = d0 >> 5, cc = (d0 >> 3) & 3;
    int sw = (row >> 1) & 3;
    size_t o = ((size_t)(kt * 2) * 2048 + row) * 32 + ((cc ^ sw) << 3);
    *(half8*)(xcs2 + o) = h;
    *(half8*)(xcs2 + o + (size_t)2048 * 32) = lo;
}

__device__ __forceinline__ float softplusf(float x) {
    return (x > 20.f) ? x : log1pf(expf(x));
}

// ---------- chunked scan ----------
__global__ __launch_bounds__(256) void scan_pass1(
    const float* __restrict__ dbu, const float* __restrict__ W_dt,
    const float* __restrict__ b_dt, const float* __restrict__ A_log,
    float* __restrict__ Sout, float* __restrict__ Pout)
{
    const int D = 2048, L = 1024, NDBU = 2080;
    const int g = blockIdx.x & 7;
    const int c = (blockIdx.x >> 3) & (NCHUNK - 1);
    const int b = blockIdx.x >> 8;
    const int d = g * 256 + threadIdx.x;

    float wdt[NSTATE], Aneg[NSTATE], s[NSTATE], P[NSTATE];
    #pragma unroll
    for (int n = 0; n < NSTATE; ++n) {
        wdt[n] = W_dt[d * NSTATE + n];
        Aneg[n] = -expf(A_log[d * NSTATE + n]);
        s[n] = 0.f; P[n] = 1.f;
    }
    const float bdt = b_dt[d];

    __shared__ float sbuf[LCHUNK][33];
    {
        int r = threadIdx.x >> 3;
        int c4 = (threadIdx.x & 7) * 4;
        float4 v = *(const float4*)(dbu + ((size_t)b * L + c * LCHUNK + r) * NDBU + c4);
        sbuf[r][c4 + 0] = v.x; sbuf[r][c4 + 1] = v.y;
        sbuf[r][c4 + 2] = v.z; sbuf[r][c4 + 3] = v.w;
    }
    __syncthreads();

    for (int li = 0; li < LCHUNK; ++li) {
        const int l = c * LCHUNK + li;
        const float u = dbu[((size_t)b * L + l) * NDBU + 32 + d];
        float accd = bdt;
        #pragma unroll
        for (int n = 0; n < NSTATE; ++n) accd = fmaf(sbuf[li][n], wdt[n], accd);
        const float delta = softplusf(accd);
        const float du = delta * u;
        #pragma unroll
        for (int n = 0; n < NSTATE; ++n) {
            float dA = expf(delta * Aneg[n]);
            s[n] = fmaf(dA, s[n], du * sbuf[li][16 + n]);
            P[n] *= dA;
        }
    }
    const size_t o = (((size_t)b * NCHUNK + c) * D + d) * NSTATE;
    #pragma unroll
    for (int n = 0; n < NSTATE; ++n) { Sout[o + n] = s[n]; Pout[o + n] = P[n]; }
}

__global__ __launch_bounds__(256) void scan_mid(
    const float* __restrict__ S, float* __restrict__ P)
{
    const int D = 2048;
    int idx = blockIdx.x * 256 + threadIdx.x;
    int n = idx & 15;
    int d = (idx >> 4) & (D - 1);
    int b = idx >> 15;
    float carry = 0.f;
    for (int c = 0; c < NCHUNK; ++c) {
        size_t o = (((size_t)b * NCHUNK + c) * D + d) * NSTATE + n;
        float Sv = S[o], Pv = P[o];
        P[o] = carry;
        carry = fmaf(Pv, carry, Sv);
    }
}

// pass2: y gated, emitted in TILED f16 hi|lo layout (Rtot=2048, K=2048)
__global__ __launch_bounds__(256) void scan_pass2(
    const float* __restrict__ dbu, const float* __restrict__ z,
    const float* __restrict__ W_dt, const float* __restrict__ b_dt,
    const float* __restrict__ A_log, const float* __restrict__ Dp,
    const float* __restrict__ CarryIn, _Float16* __restrict__ y2)
{
    const int D = 2048, L = 1024, NDBU = 2080;
    const int g = blockIdx.x & 7;
    const int c = (blockIdx.x >> 3) & (NCHUNK - 1);
    const int b = blockIdx.x >> 8;
    const int d = g * 256 + threadIdx.x;

    float wdt[NSTATE], Aneg[NSTATE], s[NSTATE];
    const size_t o = (((size_t)b * NCHUNK + c) * D + d) * NSTATE;
    #pragma unroll
    for (int n = 0; n < NSTATE; ++n) {
        wdt[n] = W_dt[d * NSTATE + n];
        Aneg[n] = -expf(A_log[d * NSTATE + n]);
        s[n] = CarryIn[o + n];
    }
    const float bdt = b_dt[d];
    const float dp = Dp[d];

    const int kt = d >> 5, cc = (d >> 3) & 3, el = d & 7;

    __shared__ float sbuf[LCHUNK][33];
    {
        int r = threadIdx.x >> 3;
        int c4 = (threadIdx.x & 7) * 4;
        float4 v = *(const float4*)(dbu + ((size_t)b * L + c * LCHUNK + r) * NDBU + c4);
        sbuf[r][c4 + 0] = v.x; sbuf[r][c4 + 1] = v.y;
        sbuf[r][c4 + 2] = v.z; sbuf[r][c4 + 3] = v.w;
    }
    __syncthreads();

    for (int li = 0; li < LCHUNK; ++li) {
        const int l = c * LCHUNK + li;
        const int row = b * L + l;
        const float u = dbu[(size_t)row * NDBU + 32 + d];
        float accd = bdt;
        #pragma unroll
        for (int n = 0; n < NSTATE; ++n) accd = fmaf(sbuf[li][n], wdt[n], accd);
        const float delta = softplusf(accd);
        const float du = delta * u;
        float sum = 0.f;
        #pragma unroll
        for (int n = 0; n < NSTATE; ++n) {
            float dA = expf(delta * Aneg[n]);
            s[n] = fmaf(dA, s[n], du * sbuf[li][16 + n]);
            sum += s[n];
        }
        const float zz = z[(size_t)row * D + d];
        const float yv = (sum + u) * dp * (zz / (1.f + expf(-zz)));
        _Float16 hv = (_Float16)yv;
        int sw = (row >> 1) & 3;
        size_t oo = ((size_t)(kt * 2) * 2048 + row) * 32 + ((cc ^ sw) << 3) + el;
        y2[oo] = hv;
        y2[oo + (size_t)2048 * 32] = (_Float16)(yv - (float)hv);
    }
}

// ---------- combine 2 split-K partials + bias ----------
__global__ __launch_bounds__(256) void combine2(
    const float* __restrict__ p1, const float* __restrict__ p2,
    const float* __restrict__ bias, float* __restrict__ out)
{
    int i = (blockIdx.x * 256 + threadIdx.x) * 4;
    int n = i & 1023;
    float4 a = *(const float4*)(p1 + i);
    float4 b = *(const float4*)(p2 + i);
    float4 bb = *(const float4*)(bias + n);
    float4 r;
    r.x = a.x + b.x + bb.x; r.y = a.y + b.y + bb.y;
    r.z = a.z + b.z + bb.z; r.w = a.w + b.w + bb.w;
    *(float4*)(out + i) = r;
}

extern "C" void kernel_launch(void* const* d_in, const int* in_sizes, int n_in,
                              void* d_out, int out_size, void* d_ws, size_t ws_size,
                              hipStream_t stream) {
    const float* x      = (const float*)d_in[0];
    const float* W_in   = (const float*)d_in[1];
    const float* b_in   = (const float*)d_in[2];
    const float* conv_w = (const float*)d_in[3];
    const float* conv_b = (const float*)d_in[4];
    const float* W_x    = (const float*)d_in[5];
    const float* b_x    = (const float*)d_in[6];
    const float* W_dt   = (const float*)d_in[7];
    const float* b_dt   = (const float*)d_in[8];
    const float* A_log  = (const float*)d_in[9];
    const float* Dp     = (const float*)d_in[10];
    const float* W_out  = (const float*)d_in[11];
    const float* b_out  = (const float*)d_in[12];
    float* out = (float*)d_out;

    // ws (bytes):
    //  z/parts @ 0        : fp32 z 16.8MB; later 2x8.4MB GEMM3 partials
    //  xc/dbu  @ 16777216 : fp32 [2048][2080]
    //  big     @ 33816576 : f16 16.8MB {Win2 -> xcs2 -> y2} (tiled)
    //  aux     @ 50593792 : f16 Wx2 [2176][4096] tiled; later S(8.4)+P(8.4)
    //  whi     @ 69468160 : f16 8.4MB {xh2 -> Wout2} (tiled)
    char* ws = (char*)d_ws;
    float*    z     = (float*)(ws);
    float*    xc    = (float*)(ws + 16777216);
    float*    dbu   = xc;
    _Float16* big   = (_Float16*)(ws + 33816576);
    _Float16* aux   = (_Float16*)(ws + 50593792);
    _Float16* whi   = (_Float16*)(ws + 69468160);

    _Float16* Win2  = big;                 // tiled [32kt][2][4096][32]
    _Float16* xh2   = whi;                 // tiled [32kt][2][2048][32]
    _Float16* xcs2  = big;                 // tiled [64kt][2][2048][32]
    _Float16* Wx2   = aux;                 // tiled [64kt][2][2176][32]
    float*    Sb    = (float*)aux;         // after GEMM2 (Wx2 dead)
    float*    Pb    = Sb + (size_t)2 * NCHUNK * 2048 * NSTATE;
    _Float16* y2    = big;                 // tiled [64kt][2][2048][32]
    _Float16* Wout2 = whi;                 // tiled [64kt][2][1024][32]
    float*    part1 = (float*)ws;          // 2 x [2048][1024] (z+dbu dead)
    float*    part2 = part1 + (size_t)2048 * 1024;

    dim3 blk(256);

    // 1. all input converters in one launch: x | W_in | W_x (tiled outputs)
    convAll<<<1024 + 2048 + 2176, blk, 0, stream>>>(x, W_in, W_x, xh2, Win2, Wx2);

    // 2. GEMM1: xz = x @ W_in.T + b_in -> xc (cols<2048), z (cols>=2048)
    //    256x128, 8 waves, grid 32x8 = 256 blocks
    hgemmT<256, 128, 2, 8, 6><<<dim3(32, 8, 1), dim3(512), 0, stream>>>(
        xh2, Win2, b_in, xc, z, 2048, 2048, 4096, 2048, 4096, 32, 0, 0);

    // 3. conv + silu -> xcs2 (tiled), merged with W_out converter (tiled)
    conv_silu_wout<<<2048 + 1024, blk, 0, stream>>>(
        xc, conv_w, conv_b, xcs2, W_out, Wout2);

    // 4. GEMM2: dbu = xcs @ W_x.T + b_x (N pad 2176; grid 17x16 = 272 blocks)
    hgemmT<128, 128, 2, 4, 8><<<dim3(17, 16, 1), blk, 0, stream>>>(
        xcs2, Wx2, b_x, dbu, (float*)nullptr, 1 << 30, 2080, 2080, 2048, 2176, 64, 0, 0);

    // 5. chunked scan -> y2 (tiled f16 hi|lo)
    scan_pass1<<<2 * NCHUNK * 8, blk, 0, stream>>>(dbu, W_dt, b_dt, A_log, Sb, Pb);
    scan_mid<<<(2 * 2048 * NSTATE) / 256, blk, 0, stream>>>(Sb, Pb);
    scan_pass2<<<2 * NCHUNK * 8, blk, 0, stream>>>(dbu, z, W_dt, b_dt, A_log, Dp, Pb, y2);

    // 6. GEMM3 (split-K=2): out = y @ W_out.T + b_out (grid 8x16x2 = 256 blocks)
    hgemmT<128, 128, 2, 4, 8><<<dim3(8, 16, 2), blk, 0, stream>>>(
        y2, Wout2, (const float*)nullptr, part1, (float*)nullptr, 1 << 30,
        1024, 1024, 2048, 1024, 32, 32, (size_t)2048 * 1024);
    combine2<<<2048, blk, 0, stream>>>(part1, part2, b_out, out);
}